// Round 4
// baseline (641.044 us; speedup 1.0000x reference)
//
#include <hip/hip_runtime.h>
#include <hip/hip_cooperative_groups.h>

namespace cg = cooperative_groups;

#define S 8192
#define D 1024
#define WINDOW 128
#define TQ 16
#define UMAX 288
#define BK 32
#define PAD 68
#define BAND 320   // band width: s in [t_tile64-128, t_tile64+192)

typedef __attribute__((ext_vector_type(8))) short short8;
typedef __attribute__((ext_vector_type(4))) float floatx4;
typedef __attribute__((ext_vector_type(4))) unsigned short ushort4v;
typedef unsigned short u16t;

struct Params {
  const float *x, *Wq, *bq, *Wk, *bk;
  float *out;
  float *xsum, *u, *v, *a, *b, *cbuf;
  u16t *xhi, *xlo, *xT, *wqth, *wqtl, *wkth, *wktl, *mh, *ml, *yh, *yl;
  float *band; u16t *Pb; float *e0d;
};

__device__ __forceinline__ float wave_sum(float v) {
  #pragma unroll
  for (int off = 32; off > 0; off >>= 1) v += __shfl_xor(v, off, 64);
  return v;
}
__device__ __forceinline__ float wave_max(float v) {
  #pragma unroll
  for (int off = 32; off > 0; off >>= 1) v = fmaxf(v, __shfl_xor(v, off, 64));
  return v;
}
__device__ __forceinline__ unsigned int f2bf_rn(float f) {
  unsigned int u = __float_as_uint(f);
  return (u + 0x7fffu + ((u >> 16) & 1u)) >> 16;
}

#define GLDS(gp, lp) __builtin_amdgcn_global_load_lds( \
    (const __attribute__((address_space(1))) void*)(gp), \
    (__attribute__((address_space(3))) void*)(lp), 16, 0, 0)

// LDS bank-conflict-free addressing for [row][32 u16] buffers staged via
// global_load_lds (linear dest): source chunk for (row r, slot s) is
// s ^ ((r>>1)&3); frag read of chunk q at row r uses slot q ^ ((r>>1)&3).

// ---------------------------------------------------------------------------
// stage bodies (shared by mega-kernel and fallback dispatches)
// ---------------------------------------------------------------------------

static __device__ __forceinline__ void zero_body(const Params& p, int zb, int tid) {
  const int total = 3 * D + 2 * S + 16;
  for (int i = zb * 256 + tid; i < total; i += 32 * 256) p.xsum[i] = 0.f;
}

static __device__ __forceinline__ void uv_body(const Params& p, int bx, int by, int tid) {
  const int i = bx * 256 + tid;
  const int n0 = by * 128;
  float us = 0.f, vs = 0.f;
  for (int n = n0; n < n0 + 128; ++n) {
    us += p.Wq[(size_t)n * D + i] * p.bk[n];
    vs += p.Wk[(size_t)n * D + i] * p.bq[n];
  }
  atomicAdd(&p.u[i], us);
  atomicAdd(&p.v[i], vs);
  if (bx == 0 && by == 0) {
    float cs = 0.f;
    for (int n = tid; n < D; n += 256) cs += p.bq[n] * p.bk[n];
    atomicAdd(p.cbuf, cs);
  }
}

static __device__ __forceinline__ void transW_body(
    const float* __restrict__ W, u16t* __restrict__ oh, u16t* __restrict__ ol,
    void* sm, int bx, int by, int t)
{
  float (*tile)[65] = reinterpret_cast<float (*)[65]>(sm);
  const int n0 = bx * 64;   // source row
  const int i0 = by * 64;   // source col
  __syncthreads();
  #pragma unroll
  for (int pp = 0; pp < 4; ++pp) {
    int r = (t >> 4) + pp * 16;
    int c = (t & 15) * 4;
    float4 vv = *(const float4*)(W + (size_t)(n0 + r) * D + i0 + c);
    tile[r][c+0] = vv.x; tile[r][c+1] = vv.y; tile[r][c+2] = vv.z; tile[r][c+3] = vv.w;
  }
  __syncthreads();
  #pragma unroll
  for (int pp = 0; pp < 4; ++pp) {
    int ii = (t >> 4) + pp * 16;
    int nn = (t & 15) * 4;
    ushort4v h, l;
    #pragma unroll
    for (int e = 0; e < 4; ++e) {
      float f = tile[nn + e][ii];
      unsigned int hb = f2bf_rn(f);
      float hf = __uint_as_float(hb << 16);
      h[e] = (u16t)hb;
      l[e] = (u16t)f2bf_rn(f - hf);
    }
    size_t idx = (size_t)(i0 + ii) * D + n0 + nn;
    *(ushort4v*)(oh + idx) = h;
    *(ushort4v*)(ol + idx) = l;
  }
}

static __device__ __forceinline__ void prep_body(const Params& p, void* sm,
                                                 int bx, int by, int t)
{
  float (*tile)[65] = reinterpret_cast<float (*)[65]>(sm);
  const int s0 = bx * 64;
  const int d0 = by * 64;
  __syncthreads();
  #pragma unroll
  for (int pp = 0; pp < 4; ++pp) {
    int r = (t >> 4) + pp * 16;
    int c = (t & 15) * 4;
    float4 vv = *(const float4*)(p.x + (size_t)(s0 + r) * D + d0 + c);
    float f[4] = {vv.x, vv.y, vv.z, vv.w};
    tile[r][c+0] = vv.x; tile[r][c+1] = vv.y; tile[r][c+2] = vv.z; tile[r][c+3] = vv.w;
    ushort4v h, l;
    #pragma unroll
    for (int e = 0; e < 4; ++e) {
      unsigned int hb = f2bf_rn(f[e]);
      float hf = __uint_as_float(hb << 16);
      h[e] = (u16t)hb;
      l[e] = (u16t)f2bf_rn(f[e] - hf);
    }
    size_t idx = (size_t)(s0 + r) * D + d0 + c;
    *(ushort4v*)(p.xhi + idx) = h;
    *(ushort4v*)(p.xlo + idx) = l;
  }
  __syncthreads();
  // transpose write
  #pragma unroll
  for (int pp = 0; pp < 4; ++pp) {
    int dd = (t >> 4) + pp * 16;
    int ss = (t & 15) * 4;
    ushort4v o;
    #pragma unroll
    for (int e = 0; e < 4; ++e) o[e] = (u16t)f2bf_rn(tile[ss + e][dd]);
    *(ushort4v*)(p.xT + (size_t)(d0 + dd) * S + s0 + ss) = o;
  }
  // reductions
  if (t < 64) {               // column sums -> xsum[d0+t]
    float s = 0.f;
    #pragma unroll 8
    for (int r = 0; r < 64; ++r) s += tile[r][t];
    atomicAdd(&p.xsum[d0 + t], s);
  } else if (t < 128) {       // a rows
    int r = t - 64;
    float s = 0.f;
    for (int c = 0; c < 64; ++c) s += tile[r][c] * p.u[d0 + c];
    atomicAdd(&p.a[s0 + r], s);
  } else if (t < 192) {       // b rows
    int r = t - 128;
    float s = 0.f;
    for (int c = 0; c < 64; ++c) s += tile[r][c] * p.v[d0 + c];
    atomicAdd(&p.b[s0 + r], s);
  }
}

static __device__ __forceinline__ void m_body(const Params& p, void* sm,
                                              int bx, int by, int tid)
{
  u16t (*Mbuf)[64 * BK] = reinterpret_cast<u16t (*)[64 * BK]>(sm);
  const int lane = tid & 63;
  const int wv   = tid >> 6;
  const int i0   = bx * 64;
  const int j0   = by * 64;

  floatx4 acc[2][2] = {};
  const int m0w = (wv & 1) * 32;
  const int n0w = (wv >> 1) * 32;
  const int srow = lane >> 2;
  const int scolw = ((lane & 3) ^ ((lane >> 3) & 3)) * 8;
  const int rs    = (((lane >> 4) ^ ((lane >> 1) & 3)) * 8);

  for (int k0 = 0; k0 < D; k0 += BK) {
    __syncthreads();
    {
      const u16t* src = (wv == 0) ? p.wqth : (wv == 1) ? p.wqtl : (wv == 2) ? p.wkth : p.wktl;
      const int base  = (wv < 2) ? i0 : j0;
      #pragma unroll
      for (int sg = 0; sg < 4; ++sg) {
        int row = base + sg * 16 + srow;
        size_t g = (size_t)row * D + k0 + scolw;
        GLDS(src + g, &Mbuf[wv][sg * 512]);
      }
    }
    __syncthreads();
    short8 ah[2], al[2], bh[2], bl[2];
    #pragma unroll
    for (int t = 0; t < 2; ++t) {
      int ar = (m0w + t * 16 + (lane & 15)) * BK + rs;
      int br = (n0w + t * 16 + (lane & 15)) * BK + rs;
      ah[t] = *(const short8*)&Mbuf[0][ar];
      al[t] = *(const short8*)&Mbuf[1][ar];
      bh[t] = *(const short8*)&Mbuf[2][br];
      bl[t] = *(const short8*)&Mbuf[3][br];
    }
    #pragma unroll
    for (int mt = 0; mt < 2; ++mt)
      #pragma unroll
      for (int nt = 0; nt < 2; ++nt) {
        acc[mt][nt] = __builtin_amdgcn_mfma_f32_16x16x32_bf16(ah[mt], bh[nt], acc[mt][nt], 0, 0, 0);
        acc[mt][nt] = __builtin_amdgcn_mfma_f32_16x16x32_bf16(ah[mt], bl[nt], acc[mt][nt], 0, 0, 0);
        acc[mt][nt] = __builtin_amdgcn_mfma_f32_16x16x32_bf16(al[mt], bh[nt], acc[mt][nt], 0, 0, 0);
      }
  }
  #pragma unroll
  for (int mt = 0; mt < 2; ++mt)
    #pragma unroll
    for (int nt = 0; nt < 2; ++nt) {
      int j = j0 + n0w + nt * 16 + (lane & 15);
      int i = i0 + m0w + mt * 16 + (lane >> 4) * 4;
      #pragma unroll
      for (int r = 0; r < 4; ++r) {
        float f = acc[mt][nt][r];
        unsigned int hb = f2bf_rn(f);
        float hf = __uint_as_float(hb << 16);
        size_t idx = (size_t)(i + r) * D + j;
        p.mh[idx] = (u16t)hb;
        p.ml[idx] = (u16t)f2bf_rn(f - hf);
      }
    }
}

// verified round-1 structure: 128x128 tile, 256 thr, 64 KB LDS
static __device__ __forceinline__ void y_body(const Params& p, void* sm,
                                              int bx, int by, int tid)
{
  u16t* Ah = (u16t*)sm;          // 2*128*32 u16 = 16 KB each
  u16t* Al = Ah + 8192;
  u16t* Bh = Al + 8192;
  u16t* Bl = Bh + 8192;

  const int lane = tid & 63;
  const int wv   = tid >> 6;
  const int s0   = bx * 128;
  const int i0   = by * 128;

  floatx4 acc[4][4] = {};
  const int m0w  = (wv & 1) * 64;
  const int n0w  = (wv >> 1) * 64;
  const int srow = lane >> 2;
  const int scolw = ((lane & 3) ^ ((lane >> 3) & 3)) * 8;
  const int rs    = (((lane >> 4) ^ ((lane >> 1) & 3)) * 8);

  for (int k0 = 0; k0 < D; k0 += 64) {
    __syncthreads();
    #pragma unroll
    for (int h = 0; h < 2; ++h) {
      #pragma unroll
      for (int sg = 0; sg < 2; ++sg) {
        int seg  = wv * 2 + sg;
        int arow = s0 + seg * 16 + srow;
        int brow = i0 + seg * 16 + srow;
        size_t ga = (size_t)arow * D + k0 + h * 32 + scolw;
        size_t gb = (size_t)brow * D + k0 + h * 32 + scolw;
        int lb = h * 4096 + seg * 512;
        GLDS(p.xhi + ga, &Ah[lb]);
        GLDS(p.xlo + ga, &Al[lb]);
        GLDS(p.mh  + gb, &Bh[lb]);
        GLDS(p.ml  + gb, &Bl[lb]);
      }
    }
    __syncthreads();
    #pragma unroll
    for (int h = 0; h < 2; ++h) {
      short8 ah[4], al[4], bh[4], bl[4];
      #pragma unroll
      for (int t = 0; t < 4; ++t) {
        int ar = h * 4096 + (m0w + t * 16 + (lane & 15)) * BK + rs;
        int br = h * 4096 + (n0w + t * 16 + (lane & 15)) * BK + rs;
        ah[t] = *(const short8*)&Ah[ar];
        al[t] = *(const short8*)&Al[ar];
        bh[t] = *(const short8*)&Bh[br];
        bl[t] = *(const short8*)&Bl[br];
      }
      #pragma unroll
      for (int mt = 0; mt < 4; ++mt)
        #pragma unroll
        for (int nt = 0; nt < 4; ++nt) {
          acc[mt][nt] = __builtin_amdgcn_mfma_f32_16x16x32_bf16(ah[mt], bh[nt], acc[mt][nt], 0, 0, 0);
          acc[mt][nt] = __builtin_amdgcn_mfma_f32_16x16x32_bf16(ah[mt], bl[nt], acc[mt][nt], 0, 0, 0);
          acc[mt][nt] = __builtin_amdgcn_mfma_f32_16x16x32_bf16(al[mt], bh[nt], acc[mt][nt], 0, 0, 0);
        }
    }
  }
  #pragma unroll
  for (int mt = 0; mt < 4; ++mt)
    #pragma unroll
    for (int nt = 0; nt < 4; ++nt) {
      int i = i0 + n0w + nt * 16 + (lane & 15);
      int s = s0 + m0w + mt * 16 + (lane >> 4) * 4;
      #pragma unroll
      for (int r = 0; r < 4; ++r) {
        float f = acc[mt][nt][r];
        unsigned int hb = f2bf_rn(f);
        float hf = __uint_as_float(hb << 16);
        size_t idx = (size_t)(s + r) * D + i;
        p.yh[idx] = (u16t)hb;
        p.yl[idx] = (u16t)f2bf_rn(f - hf);
      }
    }
}

static __device__ __forceinline__ void scores_body(const Params& p, void* sm,
                                                   int bx, int jt, int tid)
{
  u16t* Ah = (u16t*)sm;          // 2*64*32 u16 = 8 KB each
  u16t* Al = Ah + 4096;
  u16t* Bh = Al + 4096;
  u16t* Bl = Bh + 4096;

  const int lane = tid & 63;
  const int wv   = tid >> 6;
  const int t0   = bx * 64;
  const int s_base = t0 - 128 + jt * 64;
  const float cval = p.cbuf[0];

  floatx4 acc[2][2] = {};
  const int m0w  = (wv & 1) * 32;
  const int n0w  = (wv >> 1) * 32;
  const int srow = lane >> 2;
  const int scolw = ((lane & 3) ^ ((lane >> 3) & 3)) * 8;
  const int rs    = (((lane >> 4) ^ ((lane >> 1) & 3)) * 8);

  for (int k0 = 0; k0 < D; k0 += 64) {
    __syncthreads();
    #pragma unroll
    for (int h = 0; h < 2; ++h) {
      int arow = t0 + wv * 16 + srow;
      int brow = s_base + wv * 16 + srow;
      brow = min(max(brow, 0), S - 1);
      size_t ga = (size_t)arow * D + k0 + h * 32 + scolw;
      size_t gb = (size_t)brow * D + k0 + h * 32 + scolw;
      int lb = h * 2048 + wv * 512;
      GLDS(p.xhi + ga, &Ah[lb]);
      GLDS(p.xlo + ga, &Al[lb]);
      GLDS(p.yh  + gb, &Bh[lb]);
      GLDS(p.yl  + gb, &Bl[lb]);
    }
    __syncthreads();
    #pragma unroll
    for (int h = 0; h < 2; ++h) {
      short8 ah[2], al[2], bh[2], bl[2];
      #pragma unroll
      for (int t = 0; t < 2; ++t) {
        int ar = h * 2048 + (m0w + t * 16 + (lane & 15)) * BK + rs;
        int br = h * 2048 + (n0w + t * 16 + (lane & 15)) * BK + rs;
        ah[t] = *(const short8*)&Ah[ar];
        al[t] = *(const short8*)&Al[ar];
        bh[t] = *(const short8*)&Bh[br];
        bl[t] = *(const short8*)&Bl[br];
      }
      #pragma unroll
      for (int mt = 0; mt < 2; ++mt)
        #pragma unroll
        for (int nt = 0; nt < 2; ++nt) {
          acc[mt][nt] = __builtin_amdgcn_mfma_f32_16x16x32_bf16(ah[mt], bh[nt], acc[mt][nt], 0, 0, 0);
          acc[mt][nt] = __builtin_amdgcn_mfma_f32_16x16x32_bf16(ah[mt], bl[nt], acc[mt][nt], 0, 0, 0);
          acc[mt][nt] = __builtin_amdgcn_mfma_f32_16x16x32_bf16(al[mt], bh[nt], acc[mt][nt], 0, 0, 0);
        }
    }
  }
  #pragma unroll
  for (int mt = 0; mt < 2; ++mt)
    #pragma unroll
    for (int nt = 0; nt < 2; ++nt) {
      int n_loc = n0w + nt * 16 + (lane & 15);
      int s = s_base + n_loc;
      float bv = (s >= 0 && s < S) ? p.b[s] : 0.f;
      #pragma unroll
      for (int r = 0; r < 4; ++r) {
        int m_loc = m0w + mt * 16 + (lane >> 4) * 4 + r;
        int t = t0 + m_loc;
        bool inwin = (s >= t - WINDOW) && (s < t + WINDOW) && (s >= 0) && (s < S);
        float sv = inwin ? (acc[mt][nt][r] + p.a[t] + bv + cval) : 0.f;
        p.band[(size_t)t * BAND + jt * 64 + n_loc] = sv;
      }
    }
}

static __device__ __forceinline__ void softmax_body(const Params& p, int vb, int tid)
{
  const int lane = tid & 63;
  const int w    = tid >> 6;
  const int t    = vb * 4 + w;
  const float* row = p.band + (size_t)t * BAND;
  float v[5];
  float mx = 0.f;
  #pragma unroll
  for (int i = 0; i < 5; ++i) {
    v[i] = row[i * 64 + lane];
    mx = fmaxf(mx, v[i]);
  }
  mx = wave_max(mx);
  float e0 = __expf(-mx);
  float ss = 0.f;
  #pragma unroll
  for (int i = 0; i < 5; ++i) {
    v[i] = __expf(v[i] - mx);
    ss += v[i];
  }
  ss = wave_sum(ss);
  float dinv = 1.f / (ss + (float)(S - BAND) * e0);
  #pragma unroll
  for (int i = 0; i < 5; ++i)
    p.Pb[(size_t)t * BAND + i * 64 + lane] = (u16t)f2bf_rn((v[i] - e0) * dinv);
  if (lane == 0) p.e0d[t] = e0 * dinv;
}

static __device__ __forceinline__ void pv_body(const Params& p, void* sm,
                                               int bx, int by, int tid)
{
  u16t* Ab = (u16t*)sm;          // 2*64*32 u16 = 8 KB
  u16t* Bb = Ab + 4096;          // 2*128*32 u16 = 16 KB

  const int lane = tid & 63;
  const int wv   = tid >> 6;
  const int t0   = bx * 64;
  const int d0   = by * 128;
  const int origin = t0 - 128;

  floatx4 acc[2][4] = {};
  const int m0w  = (wv & 1) * 32;   // t rows within tile
  const int n0w  = (wv >> 1) * 64;  // d cols within tile
  const int srow = lane >> 2;
  const int scolw = ((lane & 3) ^ ((lane >> 3) & 3)) * 8;
  const int rs    = (((lane >> 4) ^ ((lane >> 1) & 3)) * 8);

  for (int k0 = 0; k0 < BAND; k0 += 64) {
    __syncthreads();
    #pragma unroll
    for (int h = 0; h < 2; ++h) {
      {
        int arow = t0 + wv * 16 + srow;
        size_t ga = (size_t)arow * BAND + k0 + h * 32 + scolw;
        int lb = h * 2048 + wv * 512;
        GLDS(p.Pb + ga, &Ab[lb]);
      }
      #pragma unroll
      for (int sg = 0; sg < 2; ++sg) {
        int seg  = wv * 2 + sg;
        int brow = d0 + seg * 16 + srow;
        int s_g  = origin + k0 + h * 32 + scolw;
        s_g = min(max(s_g, 0), S - 8);
        size_t gb = (size_t)brow * S + s_g;
        int lb = h * 4096 + seg * 512;
        GLDS(p.xT + gb, &Bb[lb]);
      }
    }
    __syncthreads();
    #pragma unroll
    for (int h = 0; h < 2; ++h) {
      short8 af[2], bf[4];
      #pragma unroll
      for (int t = 0; t < 2; ++t) {
        int ar = h * 2048 + (m0w + t * 16 + (lane & 15)) * BK + rs;
        af[t] = *(const short8*)&Ab[ar];
      }
      #pragma unroll
      for (int t = 0; t < 4; ++t) {
        int br = h * 4096 + (n0w + t * 16 + (lane & 15)) * BK + rs;
        bf[t] = *(const short8*)&Bb[br];
      }
      #pragma unroll
      for (int mt = 0; mt < 2; ++mt)
        #pragma unroll
        for (int nt = 0; nt < 4; ++nt)
          acc[mt][nt] = __builtin_amdgcn_mfma_f32_16x16x32_bf16(af[mt], bf[nt], acc[mt][nt], 0, 0, 0);
    }
  }
  #pragma unroll
  for (int mt = 0; mt < 2; ++mt)
    #pragma unroll
    for (int nt = 0; nt < 4; ++nt) {
      int n_g = d0 + n0w + nt * 16 + (lane & 15);
      float xs = p.xsum[n_g];
      #pragma unroll
      for (int r = 0; r < 4; ++r) {
        int m_g = t0 + m0w + mt * 16 + (lane >> 4) * 4 + r;
        p.out[(size_t)m_g * D + n_g] = acc[mt][nt][r] + p.e0d[m_g] * xs;
      }
    }
}

// ---------------------------------------------------------------------------
// ONE cooperative dispatch: all stages as virtual-block loops, grid.sync
// between dependency levels. grid 512 x 256thr, 64 KB LDS -> 2 blocks/CU.
// ---------------------------------------------------------------------------
__global__ __launch_bounds__(256, 2) void mega_kernel(Params p)
{
  __shared__ __align__(16) unsigned char sm[65536];
  cg::grid_group grid = cg::this_grid();
  const int tid = threadIdx.x;
  const int NB  = gridDim.x;

  // stage 0: transpose Wq/Wk + zero scalar region
  for (int vb = blockIdx.x; vb < 544; vb += NB) {
    if (vb < 256)      transW_body(p.Wq, p.wqth, p.wqtl, sm, vb & 15, vb >> 4, tid);
    else if (vb < 512) transW_body(p.Wk, p.wkth, p.wktl, sm, (vb - 256) & 15, (vb - 256) >> 4, tid);
    else               zero_body(p, vb - 512, tid);
  }
  grid.sync();
  // stage 1: M = WqT.Wk  ||  u/v/c
  for (int vb = blockIdx.x; vb < 288; vb += NB) {
    if (vb < 256) m_body(p, sm, vb & 15, vb >> 4, tid);
    else          uv_body(p, (vb - 256) & 3, (vb - 256) >> 2, tid);
  }
  grid.sync();
  // stage 2: prep x (hi/lo split, xT, xsum, a, b)
  for (int vb = blockIdx.x; vb < 2048; vb += NB) prep_body(p, sm, vb & 127, vb >> 7, tid);
  grid.sync();
  // stage 3: Y = x.M^T
  for (int vb = blockIdx.x; vb < 512; vb += NB) y_body(p, sm, vb & 63, vb >> 6, tid);
  grid.sync();
  // stage 4: banded scores
  for (int vb = blockIdx.x; vb < 640; vb += NB) scores_body(p, sm, vb & 127, vb >> 7, tid);
  grid.sync();
  // stage 5: softmax
  for (int vb = blockIdx.x; vb < 2048; vb += NB) softmax_body(p, vb, tid);
  grid.sync();
  // stage 6: PV + correction
  for (int vb = blockIdx.x; vb < 1024; vb += NB) pv_body(p, sm, vb & 127, vb >> 7, tid);
}

// ---------------------------------------------------------------------------
// Fallback multi-dispatch wrappers (verified round-3 behavior)
// ---------------------------------------------------------------------------
__global__ __launch_bounds__(256) void wuv_g(Params p) {
  __shared__ __align__(16) unsigned char sm[64 * 65 * 4 + 16];
  if (blockIdx.z == 2) {
    if (blockIdx.x < 4 && blockIdx.y < 8) uv_body(p, blockIdx.x, blockIdx.y, threadIdx.x);
    return;
  }
  if (blockIdx.z == 1) transW_body(p.Wk, p.wkth, p.wktl, sm, blockIdx.x, blockIdx.y, threadIdx.x);
  else                 transW_body(p.Wq, p.wqth, p.wqtl, sm, blockIdx.x, blockIdx.y, threadIdx.x);
}
__global__ __launch_bounds__(256) void prep_g(Params p) {
  __shared__ __align__(16) unsigned char sm[64 * 65 * 4 + 16];
  prep_body(p, sm, blockIdx.x, blockIdx.y, threadIdx.x);
}
__global__ __launch_bounds__(256) void m_g(Params p) {
  __shared__ __align__(16) unsigned char sm[4 * 64 * BK * 2];
  m_body(p, sm, blockIdx.x, blockIdx.y, threadIdx.x);
}
__global__ __launch_bounds__(256) void y_g(Params p) {
  __shared__ __align__(16) unsigned char sm[65536];
  y_body(p, sm, blockIdx.x, blockIdx.y, threadIdx.x);
}
__global__ __launch_bounds__(256) void scores_g(Params p) {
  __shared__ __align__(16) unsigned char sm[32768];
  scores_body(p, sm, blockIdx.x, blockIdx.y, threadIdx.x);
}
__global__ __launch_bounds__(256) void softmax_g(Params p) {
  softmax_body(p, blockIdx.x, threadIdx.x);
}
__global__ __launch_bounds__(256) void pv_g(Params p) {
  __shared__ __align__(16) unsigned char sm[24576];
  pv_body(p, sm, blockIdx.x, blockIdx.y, threadIdx.x);
}

// ---------------------------------------------------------------------------
// Small-workspace fallback path: fp32 proj + VALU attn
// ---------------------------------------------------------------------------
__global__ __launch_bounds__(256) void proj_kernel(
    const float* __restrict__ x, const float* __restrict__ Wq,
    const float* __restrict__ bqv, const float* __restrict__ Wk,
    const float* __restrict__ bkv, float* __restrict__ qout,
    float* __restrict__ kout)
{
  __shared__ __align__(16) float xs[BK][PAD];
  __shared__ __align__(16) float wqs[BK][PAD];
  __shared__ __align__(16) float wks[BK][PAD];
  const int tid = threadIdx.x;
  const int tx = tid & 15, ty = tid >> 4;
  const int t0 = blockIdx.x * 64, i0 = blockIdx.y * 64;
  float accq[4][4] = {}, acck[4][4] = {};
  const int lrow0 = tid >> 3, lc4 = (tid & 7) * 4;
  for (int k0 = 0; k0 < D; k0 += BK) {
    __syncthreads();
    #pragma unroll
    for (int pp = 0; pp < 2; ++pp) {
      int row = lrow0 + pp * 32;
      float4 a = *(const float4*)(x  + (size_t)(t0 + row) * D + k0 + lc4);
      float4 b = *(const float4*)(Wq + (size_t)(i0 + row) * D + k0 + lc4);
      float4 c = *(const float4*)(Wk + (size_t)(i0 + row) * D + k0 + lc4);
      xs [lc4+0][row]=a.x; xs [lc4+1][row]=a.y; xs [lc4+2][row]=a.z; xs [lc4+3][row]=a.w;
      wqs[lc4+0][row]=b.x; wqs[lc4+1][row]=b.y; wqs[lc4+2][row]=b.z; wqs[lc4+3][row]=b.w;
      wks[lc4+0][row]=c.x; wks[lc4+1][row]=c.y; wks[lc4+2][row]=c.z; wks[lc4+3][row]=c.w;
    }
    __syncthreads();
    #pragma unroll
    for (int kk = 0; kk < BK; ++kk) {
      float4 av = *(const float4*)&xs [kk][ty*4];
      float4 bv = *(const float4*)&wqs[kk][tx*4];
      float4 cv = *(const float4*)&wks[kk][tx*4];
      float a[4] = {av.x, av.y, av.z, av.w};
      float b[4] = {bv.x, bv.y, bv.z, bv.w};
      float c[4] = {cv.x, cv.y, cv.z, cv.w};
      #pragma unroll
      for (int r = 0; r < 4; ++r)
        #pragma unroll
        for (int cc = 0; cc < 4; ++cc) {
          accq[r][cc] = fmaf(a[r], b[cc], accq[r][cc]);
          acck[r][cc] = fmaf(a[r], c[cc], acck[r][cc]);
        }
    }
  }
  float4 bq4 = *(const float4*)(bqv + i0 + tx*4);
  float4 bk4 = *(const float4*)(bkv + i0 + tx*4);
  #pragma unroll
  for (int r = 0; r < 4; ++r) {
    int trow = t0 + ty*4 + r;
    float4 oq = { accq[r][0]+bq4.x, accq[r][1]+bq4.y, accq[r][2]+bq4.z, accq[r][3]+bq4.w };
    float4 ok = { acck[r][0]+bk4.x, acck[r][1]+bk4.y, acck[r][2]+bk4.z, acck[r][3]+bk4.w };
    *(float4*)(qout + (size_t)trow * D + i0 + tx*4) = oq;
    *(float4*)(kout + (size_t)trow * D + i0 + tx*4) = ok;
  }
}

__global__ __launch_bounds__(256) void colsum_kernel(const float* __restrict__ x,
                                                     float* __restrict__ xsum)
{
  int d = blockIdx.x * 256 + threadIdx.x;
  int tbase = blockIdx.y * 256;
  float s = 0.f;
  for (int t = 0; t < 256; ++t) s += x[(size_t)(tbase + t) * D + d];
  atomicAdd(&xsum[d], s);
}

__global__ __launch_bounds__(256) void attn_kernel(
    const float* __restrict__ x, const float* __restrict__ q,
    const float* __restrict__ kmat, const float* __restrict__ xsum,
    float* __restrict__ out)
{
  __shared__ __align__(16) float scl[TQ][UMAX];
  __shared__ float e0s[TQ], dinv[TQ];
  const int tid = threadIdx.x, lane = tid & 63, wv = tid >> 6;
  const int t0 = blockIdx.x * TQ;
  const int lo_u = max(0, t0 - WINDOW);
  const int hi_u = min(S, t0 + TQ - 1 + WINDOW);
  const int ucnt = hi_u - lo_u;
  for (int i = tid; i < TQ * UMAX; i += 256) (&scl[0][0])[i] = 0.f;
  __syncthreads();
  {
    const int tiB = wv * 4;
    float4 qf[4][4];
    #pragma unroll
    for (int g = 0; g < 4; ++g) {
      int t = t0 + tiB + g;
      #pragma unroll
      for (int j = 0; j < 4; ++j)
        qf[g][j] = *(const float4*)(q + (size_t)t * D + lane*4 + j*256);
    }
    const int wlo = max(0, t0 + tiB - WINDOW);
    const int whi = min(S, t0 + tiB + 3 + WINDOW);
    for (int s = wlo; s < whi; ++s) {
      float4 kf[4];
      #pragma unroll
      for (int j = 0; j < 4; ++j)
        kf[j] = *(const float4*)(kmat + (size_t)s * D + lane*4 + j*256);
      float acc[4];
      #pragma unroll
      for (int g = 0; g < 4; ++g) {
        float v = 0.f;
        #pragma unroll
        for (int j = 0; j < 4; ++j) {
          v = fmaf(qf[g][j].x, kf[j].x, v);
          v = fmaf(qf[g][j].y, kf[j].y, v);
          v = fmaf(qf[g][j].z, kf[j].z, v);
          v = fmaf(qf[g][j].w, kf[j].w, v);
        }
        acc[g] = v;
      }
      #pragma unroll
      for (int g = 0; g < 4; ++g) {
        float tot = wave_sum(acc[g]);
        int t = t0 + tiB + g;
        if (lane == 0 && s >= t - WINDOW && s < t + WINDOW)
          scl[tiB + g][s - lo_u] = tot;
      }
    }
  }
  __syncthreads();
  #pragma unroll
  for (int g = 0; g < 4; ++g) {
    int ti = wv * 4 + g;
    int t = t0 + ti;
    int lo = max(0, t - WINDOW), hi = min(S, t + WINDOW);
    int cnt = hi - lo, off = lo - lo_u;
    float m = 0.f;
    for (int i = lane; i < cnt; i += 64) m = fmaxf(m, scl[ti][off + i]);
    m = wave_max(m);
    float e0 = __expf(-m);
    float ssum = 0.f;
    for (int i = lane; i < cnt; i += 64) {
      float e = __expf(scl[ti][off + i] - m);
      ssum += e;
      scl[ti][off + i] = e - e0;
    }
    ssum = wave_sum(ssum);
    if (lane == 0) {
      dinv[ti] = 1.f / (ssum + (float)(S - cnt) * e0);
      e0s[ti] = e0;
    }
  }
  __syncthreads();
  {
    const int c4 = tid * 4;
    float4 acc[TQ];
    #pragma unroll
    for (int ti = 0; ti < TQ; ++ti) acc[ti] = make_float4(0.f, 0.f, 0.f, 0.f);
    for (int su = 0; su < ucnt; su += 4) {
      float4 xr[4];
      #pragma unroll
      for (int u = 0; u < 4; ++u)
        xr[u] = *(const float4*)(x + (size_t)(lo_u + su + u) * D + c4);
      #pragma unroll
      for (int ti = 0; ti < TQ; ++ti) {
        float4 w4 = *(const float4*)&scl[ti][su];
        float wvv[4] = {w4.x, w4.y, w4.z, w4.w};
        #pragma unroll
        for (int u = 0; u < 4; ++u) {
          acc[ti].x = fmaf(wvv[u], xr[u].x, acc[ti].x);
          acc[ti].y = fmaf(wvv[u], xr[u].y, acc[ti].y);
          acc[ti].z = fmaf(wvv[u], xr[u].z, acc[ti].z);
          acc[ti].w = fmaf(wvv[u], xr[u].w, acc[ti].w);
        }
      }
    }
    float4 xsv = *(const float4*)(xsum + c4);
    #pragma unroll
    for (int ti = 0; ti < TQ; ++ti) {
      float e0 = e0s[ti], di = dinv[ti];
      float4 o;
      o.x = (acc[ti].x + e0 * xsv.x) * di;
      o.y = (acc[ti].y + e0 * xsv.y) * di;
      o.z = (acc[ti].z + e0 * xsv.z) * di;
      o.w = (acc[ti].w + e0 * xsv.w) * di;
      *(float4*)(out + (size_t)(t0 + ti) * D + c4) = o;
    }
  }
}

extern "C" void kernel_launch(void* const* d_in, const int* in_sizes, int n_in,
                              void* d_out, int out_size, void* d_ws, size_t ws_size,
                              hipStream_t stream) {
  const float* x  = (const float*)d_in[0];
  const float* Wq = (const float*)d_in[1];
  const float* bq = (const float*)d_in[2];
  const float* Wk = (const float*)d_in[3];
  const float* bk = (const float*)d_in[4];
  float* outp = (float*)d_out;

  const size_t SD = (size_t)S * D;
  const size_t DD = (size_t)D * D;

  // fp32 scalar region (zeroed by stage 0 / memset in fallback)
  float* xsum = (float*)d_ws;            // D
  float* u    = xsum + D;                // D
  float* v    = u + D;                   // D
  float* a    = v + D;                   // S
  float* b    = a + S;                   // S
  float* cbuf = b + S;                   // 16
  size_t zero_bytes = (size_t)(3 * D + 2 * S + 16) * sizeof(float);

  u16t* xhi  = (u16t*)(cbuf + 16);
  u16t* xlo  = xhi + SD;
  u16t* xT   = xlo + SD;
  u16t* wqth = xT + SD;
  u16t* wqtl = wqth + DD;
  u16t* wkth = wqtl + DD;
  u16t* wktl = wkth + DD;
  u16t* mh   = wktl + DD;
  u16t* ml   = mh + DD;
  u16t* yh   = ml + DD;
  u16t* yl   = yh + SD;
  float* band = (float*)(yl + SD);                // S*BAND f32
  u16t*  Pb   = (u16t*)(band + (size_t)S * BAND); // S*BAND u16
  float* e0d  = (float*)(Pb + (size_t)S * BAND);  // S f32
  size_t needed = (size_t)((char*)(e0d + S) - (char*)d_ws);

  if (ws_size >= needed) {
    Params P;
    P.x = x; P.Wq = Wq; P.bq = bq; P.Wk = Wk; P.bk = bk; P.out = outp;
    P.xsum = xsum; P.u = u; P.v = v; P.a = a; P.b = b; P.cbuf = cbuf;
    P.xhi = xhi; P.xlo = xlo; P.xT = xT;
    P.wqth = wqth; P.wqtl = wqtl; P.wkth = wkth; P.wktl = wktl;
    P.mh = mh; P.ml = ml; P.yh = yh; P.yl = yl;
    P.band = band; P.Pb = Pb; P.e0d = e0d;

    void* kargs[] = { (void*)&P };
    hipError_t ce = hipLaunchCooperativeKernel(
        (const void*)mega_kernel, dim3(512), dim3(256), kargs, 0, stream);
    if (ce != hipSuccess) {
      (void)hipGetLastError();   // clear error state, fall back to multi-dispatch
      (void)hipMemsetAsync(d_ws, 0, zero_bytes, stream);
      wuv_g<<<dim3(16, 16, 3), 256, 0, stream>>>(P);
      prep_g<<<dim3(128, 16), 256, 0, stream>>>(P);
      m_g<<<dim3(16, 16), 256, 0, stream>>>(P);
      y_g<<<dim3(64, 8), 256, 0, stream>>>(P);
      scores_g<<<dim3(128, 5), 256, 0, stream>>>(P);
      softmax_g<<<2048, 256, 0, stream>>>(P);
      pv_g<<<dim3(128, 8), 256, 0, stream>>>(P);
    }
  } else {
    float* xs2  = (float*)d_ws;
    float* q    = xs2 + D;
    float* kbuf = q + SD;
    (void)hipMemsetAsync(xs2, 0, D * sizeof(float), stream);
    colsum_kernel<<<dim3(D / 256, S / 256), 256, 0, stream>>>(x, xs2);
    proj_kernel<<<dim3(S / 64, D / 64), 256, 0, stream>>>(x, Wq, bq, Wk, bk, q, kbuf);
    attn_kernel<<<S / TQ, 256, 0, stream>>>(x, q, kbuf, xs2, outp);
  }
}

// Round 5
// 293.207 us; speedup vs baseline: 2.1863x; 2.1863x over previous
//
#include <hip/hip_runtime.h>

#define S 8192
#define D 1024
#define WINDOW 128
#define TQ 16
#define UMAX 288
#define BK 32
#define PAD 68
#define BAND 320   // band width: s in [t_tile64-128, t_tile64+192)

typedef __attribute__((ext_vector_type(8))) short short8;
typedef __attribute__((ext_vector_type(4))) float floatx4;
typedef __attribute__((ext_vector_type(4))) unsigned short ushort4v;
typedef unsigned short u16t;

__device__ __forceinline__ float wave_sum(float v) {
  #pragma unroll
  for (int off = 32; off > 0; off >>= 1) v += __shfl_xor(v, off, 64);
  return v;
}
__device__ __forceinline__ float wave_max(float v) {
  #pragma unroll
  for (int off = 32; off > 0; off >>= 1) v = fmaxf(v, __shfl_xor(v, off, 64));
  return v;
}
__device__ __forceinline__ unsigned int f2bf_rn(float f) {
  unsigned int u = __float_as_uint(f);
  return (u + 0x7fffu + ((u >> 16) & 1u)) >> 16;
}

#define GLDS(gp, lp) __builtin_amdgcn_global_load_lds( \
    (const __attribute__((address_space(1))) void*)(gp), \
    (__attribute__((address_space(3))) void*)(lp), 16, 0, 0)

// LDS bank-conflict-free addressing for [row][32 u16] buffers staged via
// global_load_lds (linear dest).  Source col-chunk is pre-swizzled so the
// frag read (16-lane, 64B row stride) lands on distinct bank groups.
//   staging: thread loads global chunk ((lane&3) ^ ((lane>>3)&3))
//   read:    wanted chunk q=(lane>>4) lives at slot q ^ ((lane>>1)&3)

// ---------------------------------------------------------------------------
// Merged W-prep dispatch (no memset node needed):
//  z=0: transpose Wq -> wqth/wqtl     z=1: transpose Wk -> wkth/wktl
//  z=2, by==0, bx<8 : uv direct (2 n-slices, no atomics, no pre-zero)
//  z=2, by==0, bx==8: cbuf = bq.bk (in-block reduce, direct store)
//  z=2, by>=1       : zero xsum/a/b region (consumed only by NEXT dispatch)
// ---------------------------------------------------------------------------
__global__ __launch_bounds__(256) void wuv_kernel(
    const float* __restrict__ Wq, const float* __restrict__ Wk,
    const float* __restrict__ bq, const float* __restrict__ bk,
    float* __restrict__ uu, float* __restrict__ vv, float* __restrict__ cbuf,
    u16t* __restrict__ wqth, u16t* __restrict__ wqtl,
    u16t* __restrict__ wkth, u16t* __restrict__ wktl,
    float* __restrict__ zreg)
{
  __shared__ float tile[64][65];
  __shared__ float cr[4];
  const int t = threadIdx.x;
  if (blockIdx.z == 2) {
    if (blockIdx.y == 0) {
      if (blockIdx.x < 8) {          // uv: direct stores to slice nh
        const int i  = (blockIdx.x & 3) * 256 + t;
        const int nh = blockIdx.x >> 2;
        float us = 0.f, vs = 0.f;
        for (int n = nh * 512; n < nh * 512 + 512; ++n) {
          us += Wq[(size_t)n * D + i] * bk[n];
          vs += Wk[(size_t)n * D + i] * bq[n];
        }
        uu[(size_t)nh * D + i] = us;
        vv[(size_t)nh * D + i] = vs;
      } else if (blockIdx.x == 8) {  // cbuf
        float cs = 0.f;
        for (int n = t; n < D; n += 256) cs += bq[n] * bk[n];
        cs = wave_sum(cs);
        if ((t & 63) == 0) cr[t >> 6] = cs;
        __syncthreads();
        if (t == 0) cbuf[0] = cr[0] + cr[1] + cr[2] + cr[3];
      }
    } else {                         // zero xsum/a/b (D + 2S floats)
      int fb  = (blockIdx.y - 1) * 16 + blockIdx.x;  // 0..239
      int idx = fb * 256 + t;
      if (idx < D + 2 * S) zreg[idx] = 0.f;
    }
    return;
  }
  const float* W = blockIdx.z ? Wk : Wq;
  u16t* oh = blockIdx.z ? wkth : wqth;
  u16t* ol = blockIdx.z ? wktl : wqtl;
  const int n0 = blockIdx.x * 64;   // source row
  const int i0 = blockIdx.y * 64;   // source col
  #pragma unroll
  for (int p = 0; p < 4; ++p) {
    int r = (t >> 4) + p * 16;
    int c = (t & 15) * 4;
    float4 vf = *(const float4*)(W + (size_t)(n0 + r) * D + i0 + c);
    tile[r][c+0] = vf.x; tile[r][c+1] = vf.y; tile[r][c+2] = vf.z; tile[r][c+3] = vf.w;
  }
  __syncthreads();
  #pragma unroll
  for (int p = 0; p < 4; ++p) {
    int ii = (t >> 4) + p * 16;
    int nn = (t & 15) * 4;
    ushort4v h, l;
    #pragma unroll
    for (int e = 0; e < 4; ++e) {
      float f = tile[nn + e][ii];
      unsigned int hb = f2bf_rn(f);
      float hf = __uint_as_float(hb << 16);
      h[e] = (u16t)hb;
      l[e] = (u16t)f2bf_rn(f - hf);
    }
    size_t idx = (size_t)(i0 + ii) * D + n0 + nn;
    *(ushort4v*)(oh + idx) = h;
    *(ushort4v*)(ol + idx) = l;
  }
}

// ---------------------------------------------------------------------------
// prep: read x tile once -> xhi/xlo (split), xT (bf16 transpose),
//       xsum partials, a = x.u partials, b = x.v partials  (u = uu0+uu1)
// ---------------------------------------------------------------------------
__global__ __launch_bounds__(256) void prep_kernel(
    const float* __restrict__ x, const float* __restrict__ uu,
    const float* __restrict__ vv, u16t* __restrict__ xhi, u16t* __restrict__ xlo,
    u16t* __restrict__ xT, float* __restrict__ xsum,
    float* __restrict__ a, float* __restrict__ b)
{
  __shared__ float tile[64][65];
  const int s0 = blockIdx.x * 64;
  const int d0 = blockIdx.y * 64;
  const int t = threadIdx.x;
  #pragma unroll
  for (int p = 0; p < 4; ++p) {
    int r = (t >> 4) + p * 16;
    int c = (t & 15) * 4;
    float4 vf = *(const float4*)(x + (size_t)(s0 + r) * D + d0 + c);
    float f[4] = {vf.x, vf.y, vf.z, vf.w};
    tile[r][c+0] = vf.x; tile[r][c+1] = vf.y; tile[r][c+2] = vf.z; tile[r][c+3] = vf.w;
    ushort4v h, l;
    #pragma unroll
    for (int e = 0; e < 4; ++e) {
      unsigned int hb = f2bf_rn(f[e]);
      float hf = __uint_as_float(hb << 16);
      h[e] = (u16t)hb;
      l[e] = (u16t)f2bf_rn(f[e] - hf);
    }
    size_t idx = (size_t)(s0 + r) * D + d0 + c;
    *(ushort4v*)(xhi + idx) = h;
    *(ushort4v*)(xlo + idx) = l;
  }
  __syncthreads();
  // transpose write
  #pragma unroll
  for (int p = 0; p < 4; ++p) {
    int dd = (t >> 4) + p * 16;
    int ss = (t & 15) * 4;
    ushort4v o;
    #pragma unroll
    for (int e = 0; e < 4; ++e) o[e] = (u16t)f2bf_rn(tile[ss + e][dd]);
    *(ushort4v*)(xT + (size_t)(d0 + dd) * S + s0 + ss) = o;
  }
  // reductions
  if (t < 64) {               // column sums -> xsum[d0+t]
    float s = 0.f;
    #pragma unroll 8
    for (int r = 0; r < 64; ++r) s += tile[r][t];
    atomicAdd(&xsum[d0 + t], s);
  } else if (t < 128) {       // a rows
    int r = t - 64;
    float s = 0.f;
    for (int c = 0; c < 64; ++c) s += tile[r][c] * (uu[d0 + c] + uu[D + d0 + c]);
    atomicAdd(&a[s0 + r], s);
  } else if (t < 192) {       // b rows
    int r = t - 128;
    float s = 0.f;
    for (int c = 0; c < 64; ++c) s += tile[r][c] * (vv[d0 + c] + vv[D + d0 + c]);
    atomicAdd(&b[s0 + r], s);
  }
}

// ---------------------------------------------------------------------------
// M[i][j] = sum_n Wq[n][i]Wk[n][j]; hi/lo 3-term.  (swizzled LDS)
// ---------------------------------------------------------------------------
__global__ __launch_bounds__(256) void m_kernel(
    const u16t* __restrict__ wqth, const u16t* __restrict__ wqtl,
    const u16t* __restrict__ wkth, const u16t* __restrict__ wktl,
    u16t* __restrict__ mh, u16t* __restrict__ ml)
{
  __shared__ __align__(16) u16t Mbuf[4][64 * BK];  // 0:Ah 1:Al 2:Bh 3:Bl

  const int tid  = threadIdx.x;
  const int lane = tid & 63;
  const int wv   = tid >> 6;
  const int i0   = blockIdx.x * 64;
  const int j0   = blockIdx.y * 64;

  floatx4 acc[2][2] = {};
  const int m0w = (wv & 1) * 32;
  const int n0w = (wv >> 1) * 32;
  const int srow = lane >> 2;
  const int scolw = ((lane & 3) ^ ((lane >> 3) & 3)) * 8;
  const int rs    = (((lane >> 4) ^ ((lane >> 1) & 3)) * 8);

  for (int k0 = 0; k0 < D; k0 += BK) {
    __syncthreads();
    {
      const u16t* src = (wv == 0) ? wqth : (wv == 1) ? wqtl : (wv == 2) ? wkth : wktl;
      const int base  = (wv < 2) ? i0 : j0;
      #pragma unroll
      for (int sg = 0; sg < 4; ++sg) {
        int row = base + sg * 16 + srow;
        size_t g = (size_t)row * D + k0 + scolw;
        GLDS(src + g, &Mbuf[wv][sg * 512]);
      }
    }
    __syncthreads();
    short8 ah[2], al[2], bh[2], bl[2];
    #pragma unroll
    for (int t = 0; t < 2; ++t) {
      int ar = (m0w + t * 16 + (lane & 15)) * BK + rs;
      int br = (n0w + t * 16 + (lane & 15)) * BK + rs;
      ah[t] = *(const short8*)&Mbuf[0][ar];
      al[t] = *(const short8*)&Mbuf[1][ar];
      bh[t] = *(const short8*)&Mbuf[2][br];
      bl[t] = *(const short8*)&Mbuf[3][br];
    }
    #pragma unroll
    for (int mt = 0; mt < 2; ++mt)
      #pragma unroll
      for (int nt = 0; nt < 2; ++nt) {
        acc[mt][nt] = __builtin_amdgcn_mfma_f32_16x16x32_bf16(ah[mt], bh[nt], acc[mt][nt], 0, 0, 0);
        acc[mt][nt] = __builtin_amdgcn_mfma_f32_16x16x32_bf16(ah[mt], bl[nt], acc[mt][nt], 0, 0, 0);
        acc[mt][nt] = __builtin_amdgcn_mfma_f32_16x16x32_bf16(al[mt], bh[nt], acc[mt][nt], 0, 0, 0);
      }
  }
  #pragma unroll
  for (int mt = 0; mt < 2; ++mt)
    #pragma unroll
    for (int nt = 0; nt < 2; ++nt) {
      int j = j0 + n0w + nt * 16 + (lane & 15);
      int i = i0 + m0w + mt * 16 + (lane >> 4) * 4;
      #pragma unroll
      for (int r = 0; r < 4; ++r) {
        float f = acc[mt][nt][r];
        unsigned int hb = f2bf_rn(f);
        float hf = __uint_as_float(hb << 16);
        size_t idx = (size_t)(i + r) * D + j;
        mh[idx] = (u16t)hb;
        ml[idx] = (u16t)f2bf_rn(f - hf);
      }
    }
}

// ---------------------------------------------------------------------------
// Y[s][i] = sum_j x[s][j]*M[i][j]; hi/lo 3-term. BK=64 staged as two
// interleaved 32-halves; swizzled LDS.  (verified round-1 structure)
// ---------------------------------------------------------------------------
__global__ __launch_bounds__(256) void y_kernel(
    const u16t* __restrict__ xhi, const u16t* __restrict__ xlo,
    const u16t* __restrict__ mhp, const u16t* __restrict__ mlp,
    u16t* __restrict__ yh, u16t* __restrict__ yl)
{
  __shared__ __align__(16) u16t Ah[2 * 128 * BK];
  __shared__ __align__(16) u16t Al[2 * 128 * BK];
  __shared__ __align__(16) u16t Bh[2 * 128 * BK];
  __shared__ __align__(16) u16t Bl[2 * 128 * BK];

  const int tid  = threadIdx.x;
  const int lane = tid & 63;
  const int wv   = tid >> 6;
  const int s0   = blockIdx.x * 128;
  const int i0   = blockIdx.y * 128;

  floatx4 acc[4][4] = {};
  const int m0w  = (wv & 1) * 64;
  const int n0w  = (wv >> 1) * 64;
  const int srow = lane >> 2;
  const int scolw = ((lane & 3) ^ ((lane >> 3) & 3)) * 8;
  const int rs    = (((lane >> 4) ^ ((lane >> 1) & 3)) * 8);

  for (int k0 = 0; k0 < D; k0 += 64) {
    __syncthreads();
    #pragma unroll
    for (int h = 0; h < 2; ++h) {
      #pragma unroll
      for (int sg = 0; sg < 2; ++sg) {
        int seg  = wv * 2 + sg;
        int arow = s0 + seg * 16 + srow;
        int brow = i0 + seg * 16 + srow;
        size_t ga = (size_t)arow * D + k0 + h * 32 + scolw;
        size_t gb = (size_t)brow * D + k0 + h * 32 + scolw;
        int lb = h * 4096 + seg * 512;
        GLDS(xhi + ga, &Ah[lb]);
        GLDS(xlo + ga, &Al[lb]);
        GLDS(mhp + gb, &Bh[lb]);
        GLDS(mlp + gb, &Bl[lb]);
      }
    }
    __syncthreads();
    #pragma unroll
    for (int h = 0; h < 2; ++h) {
      short8 ah[4], al[4], bh[4], bl[4];
      #pragma unroll
      for (int t = 0; t < 4; ++t) {
        int ar = h * 4096 + (m0w + t * 16 + (lane & 15)) * BK + rs;
        int br = h * 4096 + (n0w + t * 16 + (lane & 15)) * BK + rs;
        ah[t] = *(const short8*)&Ah[ar];
        al[t] = *(const short8*)&Al[ar];
        bh[t] = *(const short8*)&Bh[br];
        bl[t] = *(const short8*)&Bl[br];
      }
      #pragma unroll
      for (int mt = 0; mt < 4; ++mt)
        #pragma unroll
        for (int nt = 0; nt < 4; ++nt) {
          acc[mt][nt] = __builtin_amdgcn_mfma_f32_16x16x32_bf16(ah[mt], bh[nt], acc[mt][nt], 0, 0, 0);
          acc[mt][nt] = __builtin_amdgcn_mfma_f32_16x16x32_bf16(ah[mt], bl[nt], acc[mt][nt], 0, 0, 0);
          acc[mt][nt] = __builtin_amdgcn_mfma_f32_16x16x32_bf16(al[mt], bh[nt], acc[mt][nt], 0, 0, 0);
        }
    }
  }
  #pragma unroll
  for (int mt = 0; mt < 4; ++mt)
    #pragma unroll
    for (int nt = 0; nt < 4; ++nt) {
      int i = i0 + n0w + nt * 16 + (lane & 15);
      int s = s0 + m0w + mt * 16 + (lane >> 4) * 4;
      #pragma unroll
      for (int r = 0; r < 4; ++r) {
        float f = acc[mt][nt][r];
        unsigned int hb = f2bf_rn(f);
        float hf = __uint_as_float(hb << 16);
        size_t idx = (size_t)(s + r) * D + i;
        yh[idx] = (u16t)hb;
        yl[idx] = (u16t)f2bf_rn(f - hf);
      }
    }
}

// ---------------------------------------------------------------------------
// Banded scores, 64x64 tiles: band[t][j] = x_t.Y_s + a[t] + b[s] + c
// (s = (t&~63) - 128 + j, j in [0,320)), hi/lo 3-term, swizzled LDS.
// ---------------------------------------------------------------------------
__global__ __launch_bounds__(256) void scores_kernel(
    const u16t* __restrict__ xhi, const u16t* __restrict__ xlo,
    const u16t* __restrict__ yh, const u16t* __restrict__ yl,
    const float* __restrict__ a, const float* __restrict__ b,
    const float* __restrict__ cbuf, float* __restrict__ band)
{
  __shared__ __align__(16) u16t Ah[2 * 64 * BK];
  __shared__ __align__(16) u16t Al[2 * 64 * BK];
  __shared__ __align__(16) u16t Bh[2 * 64 * BK];
  __shared__ __align__(16) u16t Bl[2 * 64 * BK];

  const int tid  = threadIdx.x;
  const int lane = tid & 63;
  const int wv   = tid >> 6;
  const int t0   = blockIdx.x * 64;
  const int jt   = blockIdx.y;              // 0..4
  const int s_base = t0 - 128 + jt * 64;
  const float cval = cbuf[0];

  floatx4 acc[2][2] = {};
  const int m0w  = (wv & 1) * 32;
  const int n0w  = (wv >> 1) * 32;
  const int srow = lane >> 2;
  const int scolw = ((lane & 3) ^ ((lane >> 3) & 3)) * 8;
  const int rs    = (((lane >> 4) ^ ((lane >> 1) & 3)) * 8);

  for (int k0 = 0; k0 < D; k0 += 64) {
    __syncthreads();
    #pragma unroll
    for (int h = 0; h < 2; ++h) {
      int arow = t0 + wv * 16 + srow;
      int brow = s_base + wv * 16 + srow;
      brow = min(max(brow, 0), S - 1);
      size_t ga = (size_t)arow * D + k0 + h * 32 + scolw;
      size_t gb = (size_t)brow * D + k0 + h * 32 + scolw;
      int lb = h * 2048 + wv * 512;
      GLDS(xhi + ga, &Ah[lb]);
      GLDS(xlo + ga, &Al[lb]);
      GLDS(yh + gb, &Bh[lb]);
      GLDS(yl + gb, &Bl[lb]);
    }
    __syncthreads();
    #pragma unroll
    for (int h = 0; h < 2; ++h) {
      short8 ah[2], al[2], bh[2], bl[2];
      #pragma unroll
      for (int t = 0; t < 2; ++t) {
        int ar = h * 2048 + (m0w + t * 16 + (lane & 15)) * BK + rs;
        int br = h * 2048 + (n0w + t * 16 + (lane & 15)) * BK + rs;
        ah[t] = *(const short8*)&Ah[ar];
        al[t] = *(const short8*)&Al[ar];
        bh[t] = *(const short8*)&Bh[br];
        bl[t] = *(const short8*)&Bl[br];
      }
      #pragma unroll
      for (int mt = 0; mt < 2; ++mt)
        #pragma unroll
        for (int nt = 0; nt < 2; ++nt) {
          acc[mt][nt] = __builtin_amdgcn_mfma_f32_16x16x32_bf16(ah[mt], bh[nt], acc[mt][nt], 0, 0, 0);
          acc[mt][nt] = __builtin_amdgcn_mfma_f32_16x16x32_bf16(ah[mt], bl[nt], acc[mt][nt], 0, 0, 0);
          acc[mt][nt] = __builtin_amdgcn_mfma_f32_16x16x32_bf16(al[mt], bh[nt], acc[mt][nt], 0, 0, 0);
        }
    }
  }
  #pragma unroll
  for (int mt = 0; mt < 2; ++mt)
    #pragma unroll
    for (int nt = 0; nt < 2; ++nt) {
      int n_loc = n0w + nt * 16 + (lane & 15);
      int s = s_base + n_loc;
      float bv = (s >= 0 && s < S) ? b[s] : 0.f;
      #pragma unroll
      for (int r = 0; r < 4; ++r) {
        int m_loc = m0w + mt * 16 + (lane >> 4) * 4 + r;
        int t = t0 + m_loc;
        bool inwin = (s >= t - WINDOW) && (s < t + WINDOW) && (s >= 0) && (s < S);
        float sv = inwin ? (acc[mt][nt][r] + a[t] + bv + cval) : 0.f;
        band[(size_t)t * BAND + jt * 64 + n_loc] = sv;
      }
    }
}

// ---------------------------------------------------------------------------
// PV + fused softmax: block (t0 64-rows, d0 128-cols).
// Phase 1: softmax over band rows t0..t0+63 -> P bf16 in LDS (stride 328,
//          pad shifts rows by 4 banks -> conflict-free frag reads), e0*dinv.
// Phase 2: out[t][d] = sum_j P[t][j]*xT[d][origin+j] + e0d[t]*xsum[d].
// ---------------------------------------------------------------------------
#define PSTR 328
__global__ __launch_bounds__(256) void pv_kernel(
    const float* __restrict__ band, const u16t* __restrict__ xT,
    const float* __restrict__ xsum, float* __restrict__ out)
{
  __shared__ __align__(16) u16t Pl[64 * PSTR];      // 41 KB
  __shared__ __align__(16) u16t Bb[2 * 128 * BK];   // 16 KB
  __shared__ float e0s[64];

  const int tid  = threadIdx.x;
  const int lane = tid & 63;
  const int wv   = tid >> 6;
  const int t0   = blockIdx.x * 64;
  const int d0   = blockIdx.y * 128;
  const int origin = t0 - 128;

  // ---- phase 1: softmax (each wave: 16 rows) ----
  for (int it = 0; it < 16; ++it) {
    int rloc = it * 4 + wv;
    const float* row = band + (size_t)(t0 + rloc) * BAND;
    float v[5];
    float mx = 0.f;
    #pragma unroll
    for (int i = 0; i < 5; ++i) {
      v[i] = row[i * 64 + lane];
      mx = fmaxf(mx, v[i]);
    }
    mx = wave_max(mx);
    float e0 = __expf(-mx);
    float ss = 0.f;
    #pragma unroll
    for (int i = 0; i < 5; ++i) {
      v[i] = __expf(v[i] - mx);
      ss += v[i];
    }
    ss = wave_sum(ss);
    float dinv = 1.f / (ss + (float)(S - BAND) * e0);
    #pragma unroll
    for (int i = 0; i < 5; ++i)
      Pl[rloc * PSTR + i * 64 + lane] = (u16t)f2bf_rn((v[i] - e0) * dinv);
    if (lane == 0) e0s[rloc] = e0 * dinv;
  }

  // ---- phase 2: PV ----
  floatx4 acc[2][4] = {};
  const int m0w  = (wv & 1) * 32;   // t rows within tile
  const int n0w  = (wv >> 1) * 64;  // d cols within tile
  const int srow = lane >> 2;
  const int scolw = ((lane & 3) ^ ((lane >> 3) & 3)) * 8;
  const int rs    = (((lane >> 4) ^ ((lane >> 1) & 3)) * 8);   // B (staged) only
  const int fr    = lane & 15;
  const int qA    = (lane >> 4) * 8;                           // A: plain chunk

  for (int k0 = 0; k0 < BAND; k0 += 64) {
    __syncthreads();
    #pragma unroll
    for (int h = 0; h < 2; ++h) {
      #pragma unroll
      for (int sg = 0; sg < 2; ++sg) {
        int seg  = wv * 2 + sg;
        int brow = d0 + seg * 16 + srow;
        int s_g  = origin + k0 + h * 32 + scolw;
        s_g = min(max(s_g, 0), S - 8);
        size_t gb = (size_t)brow * S + s_g;
        GLDS(xT + gb, &Bb[h * 4096 + seg * 512]);
      }
    }
    __syncthreads();
    #pragma unroll
    for (int h = 0; h < 2; ++h) {
      short8 af[2], bf[4];
      #pragma unroll
      for (int t = 0; t < 2; ++t)
        af[t] = *(const short8*)&Pl[(m0w + t * 16 + fr) * PSTR + k0 + h * 32 + qA];
      #pragma unroll
      for (int t = 0; t < 4; ++t)
        bf[t] = *(const short8*)&Bb[h * 4096 + (n0w + t * 16 + fr) * BK + rs];
      #pragma unroll
      for (int mt = 0; mt < 2; ++mt)
        #pragma unroll
        for (int nt = 0; nt < 4; ++nt)
          acc[mt][nt] = __builtin_amdgcn_mfma_f32_16x16x32_bf16(af[mt], bf[nt], acc[mt][nt], 0, 0, 0);
    }
  }
  #pragma unroll
  for (int mt = 0; mt < 2; ++mt)
    #pragma unroll
    for (int nt = 0; nt < 4; ++nt) {
      int n_g = d0 + n0w + nt * 16 + fr;
      float xs = xsum[n_g];
      #pragma unroll
      for (int r = 0; r < 4; ++r) {
        int rloc = m0w + mt * 16 + (lane >> 4) * 4 + r;
        out[(size_t)(t0 + rloc) * D + n_g] = acc[mt][nt][r] + e0s[rloc] * xs;
      }
    }
}

// ---------------------------------------------------------------------------
// Fallback path (small workspace): fp32 proj + VALU attn
// ---------------------------------------------------------------------------
__global__ __launch_bounds__(256) void proj_kernel(
    const float* __restrict__ x, const float* __restrict__ Wq,
    const float* __restrict__ bqv, const float* __restrict__ Wk,
    const float* __restrict__ bkv, float* __restrict__ qout,
    float* __restrict__ kout)
{
  __shared__ __align__(16) float xs[BK][PAD];
  __shared__ __align__(16) float wqs[BK][PAD];
  __shared__ __align__(16) float wks[BK][PAD];
  const int tid = threadIdx.x;
  const int tx = tid & 15, ty = tid >> 4;
  const int t0 = blockIdx.x * 64, i0 = blockIdx.y * 64;
  float accq[4][4] = {}, acck[4][4] = {};
  const int lrow0 = tid >> 3, lc4 = (tid & 7) * 4;
  for (int k0 = 0; k0 < D; k0 += BK) {
    __syncthreads();
    #pragma unroll
    for (int p = 0; p < 2; ++p) {
      int row = lrow0 + p * 32;
      float4 a = *(const float4*)(x  + (size_t)(t0 + row) * D + k0 + lc4);
      float4 b = *(const float4*)(Wq + (size_t)(i0 + row) * D + k0 + lc4);
      float4 c = *(const float4*)(Wk + (size_t)(i0 + row) * D + k0 + lc4);
      xs [lc4+0][row]=a.x; xs [lc4+1][row]=a.y; xs [lc4+2][row]=a.z; xs [lc4+3][row]=a.w;
      wqs[lc4+0][row]=b.x; wqs[lc4+1][row]=b.y; wqs[lc4+2][row]=b.z; wqs[lc4+3][row]=b.w;
      wks[lc4+0][row]=c.x; wks[lc4+1][row]=c.y; wks[lc4+2][row]=c.z; wks[lc4+3][row]=c.w;
    }
    __syncthreads();
    #pragma unroll
    for (int kk = 0; kk < BK; ++kk) {
      float4 av = *(const float4*)&xs [kk][ty*4];
      float4 bv = *(const float4*)&wqs[kk][tx*4];
      float4 cv = *(const float4*)&wks[kk][tx*4];
      float a[4] = {av.x, av.y, av.z, av.w};
      float b[4] = {bv.x, bv.y, bv.z, bv.w};
      float c[4] = {cv.x, cv.y, cv.z, cv.w};
      #pragma unroll
      for (int r = 0; r < 4; ++r)
        #pragma unroll
        for (int cc = 0; cc < 4; ++cc) {
          accq[r][cc] = fmaf(a[r], b[cc], accq[r][cc]);
          acck[r][cc] = fmaf(a[r], c[cc], acck[r][cc]);
        }
    }
  }
  float4 bq4 = *(const float4*)(bqv + i0 + tx*4);
  float4 bk4 = *(const float4*)(bkv + i0 + tx*4);
  #pragma unroll
  for (int r = 0; r < 4; ++r) {
    int trow = t0 + ty*4 + r;
    float4 oq = { accq[r][0]+bq4.x, accq[r][1]+bq4.y, accq[r][2]+bq4.z, accq[r][3]+bq4.w };
    float4 ok = { acck[r][0]+bk4.x, acck[r][1]+bk4.y, acck[r][2]+bk4.z, acck[r][3]+bk4.w };
    *(float4*)(qout + (size_t)trow * D + i0 + tx*4) = oq;
    *(float4*)(kout + (size_t)trow * D + i0 + tx*4) = ok;
  }
}

__global__ __launch_bounds__(256) void colsum_kernel(const float* __restrict__ x,
                                                     float* __restrict__ xsum)
{
  int d = blockIdx.x * 256 + threadIdx.x;
  int tbase = blockIdx.y * 256;
  float s = 0.f;
  for (int t = 0; t < 256; ++t) s += x[(size_t)(tbase + t) * D + d];
  atomicAdd(&xsum[d], s);
}

__global__ __launch_bounds__(256) void attn_kernel(
    const float* __restrict__ x, const float* __restrict__ q,
    const float* __restrict__ kmat, const float* __restrict__ xsum,
    float* __restrict__ out)
{
  __shared__ __align__(16) float scl[TQ][UMAX];
  __shared__ float e0s[TQ], dinv[TQ];
  const int tid = threadIdx.x, lane = tid & 63, wv = tid >> 6;
  const int t0 = blockIdx.x * TQ;
  const int lo_u = max(0, t0 - WINDOW);
  const int hi_u = min(S, t0 + TQ - 1 + WINDOW);
  const int ucnt = hi_u - lo_u;
  for (int i = tid; i < TQ * UMAX; i += 256) (&scl[0][0])[i] = 0.f;
  __syncthreads();
  {
    const int tiB = wv * 4;
    float4 qf[4][4];
    #pragma unroll
    for (int g = 0; g < 4; ++g) {
      int t = t0 + tiB + g;
      #pragma unroll
      for (int j = 0; j < 4; ++j)
        qf[g][j] = *(const float4*)(q + (size_t)t * D + lane*4 + j*256);
    }
    const int wlo = max(0, t0 + tiB - WINDOW);
    const int whi = min(S, t0 + tiB + 3 + WINDOW);
    for (int s = wlo; s < whi; ++s) {
      float4 kf[4];
      #pragma unroll
      for (int j = 0; j < 4; ++j)
        kf[j] = *(const float4*)(kmat + (size_t)s * D + lane*4 + j*256);
      float acc[4];
      #pragma unroll
      for (int g = 0; g < 4; ++g) {
        float v = 0.f;
        #pragma unroll
        for (int j = 0; j < 4; ++j) {
          v = fmaf(qf[g][j].x, kf[j].x, v);
          v = fmaf(qf[g][j].y, kf[j].y, v);
          v = fmaf(qf[g][j].z, kf[j].z, v);
          v = fmaf(qf[g][j].w, kf[j].w, v);
        }
        acc[g] = v;
      }
      #pragma unroll
      for (int g = 0; g < 4; ++g) {
        float tot = wave_sum(acc[g]);
        int t = t0 + tiB + g;
        if (lane == 0 && s >= t - WINDOW && s < t + WINDOW)
          scl[tiB + g][s - lo_u] = tot;
      }
    }
  }
  __syncthreads();
  #pragma unroll
  for (int g = 0; g < 4; ++g) {
    int ti = wv * 4 + g;
    int t = t0 + ti;
    int lo = max(0, t - WINDOW), hi = min(S, t + WINDOW);
    int cnt = hi - lo, off = lo - lo_u;
    float m = 0.f;
    for (int i = lane; i < cnt; i += 64) m = fmaxf(m, scl[ti][off + i]);
    m = wave_max(m);
    float e0 = __expf(-m);
    float ssum = 0.f;
    for (int i = lane; i < cnt; i += 64) {
      float e = __expf(scl[ti][off + i] - m);
      ssum += e;
      scl[ti][off + i] = e - e0;
    }
    ssum = wave_sum(ssum);
    if (lane == 0) {
      dinv[ti] = 1.f / (ssum + (float)(S - cnt) * e0);
      e0s[ti] = e0;
    }
  }
  __syncthreads();
  {
    const int c4 = tid * 4;
    float4 acc[TQ];
    #pragma unroll
    for (int ti = 0; ti < TQ; ++ti) acc[ti] = make_float4(0.f, 0.f, 0.f, 0.f);
    for (int su = 0; su < ucnt; su += 4) {
      float4 xr[4];
      #pragma unroll
      for (int u = 0; u < 4; ++u)
        xr[u] = *(const float4*)(x + (size_t)(lo_u + su + u) * D + c4);
      #pragma unroll
      for (int ti = 0; ti < TQ; ++ti) {
        float4 w4 = *(const float4*)&scl[ti][su];
        float wvv[4] = {w4.x, w4.y, w4.z, w4.w};
        #pragma unroll
        for (int u = 0; u < 4; ++u) {
          acc[ti].x = fmaf(wvv[u], xr[u].x, acc[ti].x);
          acc[ti].y = fmaf(wvv[u], xr[u].y, acc[ti].y);
          acc[ti].z = fmaf(wvv[u], xr[u].z, acc[ti].z);
          acc[ti].w = fmaf(wvv[u], xr[u].w, acc[ti].w);
        }
      }
    }
    float4 xsv = *(const float4*)(xsum + c4);
    #pragma unroll
    for (int ti = 0; ti < TQ; ++ti) {
      float e0 = e0s[ti], di = dinv[ti];
      float4 o;
      o.x = (acc[ti].x + e0 * xsv.x) * di;
      o.y = (acc[ti].y + e0 * xsv.y) * di;
      o.z = (acc[ti].z + e0 * xsv.z) * di;
      o.w = (acc[ti].w + e0 * xsv.w) * di;
      *(float4*)(out + (size_t)(t0 + ti) * D + c4) = o;
    }
  }
}

extern "C" void kernel_launch(void* const* d_in, const int* in_sizes, int n_in,
                              void* d_out, int out_size, void* d_ws, size_t ws_size,
                              hipStream_t stream) {
  const float* x  = (const float*)d_in[0];
  const float* Wq = (const float*)d_in[1];
  const float* bq = (const float*)d_in[2];
  const float* Wk = (const float*)d_in[3];
  const float* bk = (const float*)d_in[4];
  float* outp = (float*)d_out;

  const size_t SD = (size_t)S * D;
  const size_t DD = (size_t)D * D;

  // fp32 scalar region: [xsum D][a S][b S] (zeroed in wuv) [uu 2D][vv 2D][cbuf 16]
  float* xsum = (float*)d_ws;            // D
  float* a    = xsum + D;                // S
  float* b    = a + S;                   // S
  float* uu   = b + S;                   // 2D (two n-slices)
  float* vv   = uu + 2 * D;              // 2D
  float* cbuf = vv + 2 * D;              // 16

  u16t* xhi  = (u16t*)(cbuf + 16);
  u16t* xlo  = xhi + SD;
  u16t* xT   = xlo + SD;
  u16t* wqth = xT + SD;
  u16t* wqtl = wqth + DD;
  u16t* wkth = wqtl + DD;
  u16t* wktl = wkth + DD;
  u16t* mh   = wktl + DD;
  u16t* ml   = mh + DD;
  u16t* yh   = ml + DD;
  u16t* yl   = yh + SD;
  float* band = (float*)(yl + SD);                // S*BAND f32
  size_t needed = (size_t)((char*)(band + (size_t)S * BAND) - (char*)d_ws);

  if (ws_size >= needed) {
    wuv_kernel<<<dim3(16, 16, 3), 256, 0, stream>>>(
        Wq, Wk, bq, bk, uu, vv, cbuf, wqth, wqtl, wkth, wktl, xsum);
    prep_kernel<<<dim3(S / 64, D / 64), 256, 0, stream>>>(x, uu, vv, xhi, xlo, xT, xsum, a, b);
    m_kernel<<<dim3(D / 64, D / 64), 256, 0, stream>>>(wqth, wqtl, wkth, wktl, mh, ml);
    y_kernel<<<dim3(S / 128, D / 128), 256, 0, stream>>>(xhi, xlo, mh, ml, yh, yl);
    scores_kernel<<<dim3(S / 64, 5), 256, 0, stream>>>(xhi, xlo, yh, yl, a, b, cbuf, band);
    pv_kernel<<<dim3(S / 64, D / 128), 256, 0, stream>>>(band, xT, xsum, outp);
  } else {
    float* xs2  = (float*)d_ws;
    float* q    = xs2 + D;
    float* kbuf = q + SD;
    (void)hipMemsetAsync(xs2, 0, D * sizeof(float), stream);
    colsum_kernel<<<dim3(D / 256, S / 256), 256, 0, stream>>>(x, xs2);
    proj_kernel<<<dim3(S / 64, D / 64), 256, 0, stream>>>(x, Wq, bq, Wk, bk, q, kbuf);
    attn_kernel<<<S / TQ, 256, 0, stream>>>(x, q, kbuf, xs2, outp);
  }
}

// Round 6
// 289.667 us; speedup vs baseline: 2.2130x; 1.0122x over previous
//
#include <hip/hip_runtime.h>

#define S 8192
#define D 1024
#define WINDOW 128
#define TQ 16
#define UMAX 288
#define BK 32
#define PAD 68
#define BAND 320   // band width: s in [t_tile64-128, t_tile64+192)

typedef __attribute__((ext_vector_type(8))) short short8;
typedef __attribute__((ext_vector_type(4))) float floatx4;
typedef __attribute__((ext_vector_type(16))) float floatx16;
typedef __attribute__((ext_vector_type(4))) unsigned short ushort4v;
typedef unsigned short u16t;

__device__ __forceinline__ float wave_sum(float v) {
  #pragma unroll
  for (int off = 32; off > 0; off >>= 1) v += __shfl_xor(v, off, 64);
  return v;
}
__device__ __forceinline__ float wave_max(float v) {
  #pragma unroll
  for (int off = 32; off > 0; off >>= 1) v = fmaxf(v, __shfl_xor(v, off, 64));
  return v;
}
__device__ __forceinline__ unsigned int f2bf_rn(float f) {
  unsigned int u = __float_as_uint(f);
  return (u + 0x7fffu + ((u >> 16) & 1u)) >> 16;
}

#define GLDS(gp, lp) __builtin_amdgcn_global_load_lds( \
    (const __attribute__((address_space(1))) void*)(gp), \
    (__attribute__((address_space(3))) void*)(lp), 16, 0, 0)

// LDS [row][32 u16] staged via global_load_lds (linear dest), source chunk
// pre-swizzled: LDS[r][slot s] holds global chunk s ^ ((r>>1)&3).
// 32x32x16 frag read: row = base + (lane&31), chunk c = ks*2 + (lane>>5),
// slot = c ^ ((lane>>1)&3)  -> 64-lane b128 read covers each bank exactly
// twice (2-way aliasing = free).
// C/D layout (verified): col = lane&31, row = (r&3) + 8*(r>>2) + 4*(lane>>5).

// ---------------------------------------------------------------------------
// Merged W-prep dispatch:
//  z=0: transpose Wq -> wqth/wqtl     z=1: transpose Wk -> wkth/wktl
//  z=2, by==0, bx<8 : uv direct (2 n-slices, no atomics)
//  z=2, by==0, bx==8: cbuf = bq.bk
//  z=2, by>=1       : zero xsum/a/b region (consumed only by NEXT dispatch)
// ---------------------------------------------------------------------------
__global__ __launch_bounds__(256) void wuv_kernel(
    const float* __restrict__ Wq, const float* __restrict__ Wk,
    const float* __restrict__ bq, const float* __restrict__ bk,
    float* __restrict__ uu, float* __restrict__ vv, float* __restrict__ cbuf,
    u16t* __restrict__ wqth, u16t* __restrict__ wqtl,
    u16t* __restrict__ wkth, u16t* __restrict__ wktl,
    float* __restrict__ zreg)
{
  __shared__ float tile[64][65];
  __shared__ float cr[4];
  const int t = threadIdx.x;
  if (blockIdx.z == 2) {
    if (blockIdx.y == 0) {
      if (blockIdx.x < 8) {          // uv: direct stores to slice nh
        const int i  = (blockIdx.x & 3) * 256 + t;
        const int nh = blockIdx.x >> 2;
        float us = 0.f, vs = 0.f;
        for (int n = nh * 512; n < nh * 512 + 512; ++n) {
          us += Wq[(size_t)n * D + i] * bk[n];
          vs += Wk[(size_t)n * D + i] * bq[n];
        }
        uu[(size_t)nh * D + i] = us;
        vv[(size_t)nh * D + i] = vs;
      } else if (blockIdx.x == 8) {  // cbuf
        float cs = 0.f;
        for (int n = t; n < D; n += 256) cs += bq[n] * bk[n];
        cs = wave_sum(cs);
        if ((t & 63) == 0) cr[t >> 6] = cs;
        __syncthreads();
        if (t == 0) cbuf[0] = cr[0] + cr[1] + cr[2] + cr[3];
      }
    } else {                         // zero xsum/a/b (D + 2S floats)
      int fb  = (blockIdx.y - 1) * 16 + blockIdx.x;  // 0..239
      int idx = fb * 256 + t;
      if (idx < D + 2 * S) zreg[idx] = 0.f;
    }
    return;
  }
  const float* W = blockIdx.z ? Wk : Wq;
  u16t* oh = blockIdx.z ? wkth : wqth;
  u16t* ol = blockIdx.z ? wktl : wqtl;
  const int n0 = blockIdx.x * 64;   // source row
  const int i0 = blockIdx.y * 64;   // source col
  #pragma unroll
  for (int p = 0; p < 4; ++p) {
    int r = (t >> 4) + p * 16;
    int c = (t & 15) * 4;
    float4 vf = *(const float4*)(W + (size_t)(n0 + r) * D + i0 + c);
    tile[r][c+0] = vf.x; tile[r][c+1] = vf.y; tile[r][c+2] = vf.z; tile[r][c+3] = vf.w;
  }
  __syncthreads();
  #pragma unroll
  for (int p = 0; p < 4; ++p) {
    int ii = (t >> 4) + p * 16;
    int nn = (t & 15) * 4;
    ushort4v h, l;
    #pragma unroll
    for (int e = 0; e < 4; ++e) {
      float f = tile[nn + e][ii];
      unsigned int hb = f2bf_rn(f);
      float hf = __uint_as_float(hb << 16);
      h[e] = (u16t)hb;
      l[e] = (u16t)f2bf_rn(f - hf);
    }
    size_t idx = (size_t)(i0 + ii) * D + n0 + nn;
    *(ushort4v*)(oh + idx) = h;
    *(ushort4v*)(ol + idx) = l;
  }
}

// ---------------------------------------------------------------------------
// prep: read x tile once -> xhi/xlo (split), xT (bf16 transpose),
//       xsum partials, a = x.u partials, b = x.v partials  (u = uu0+uu1)
// ---------------------------------------------------------------------------
__global__ __launch_bounds__(256) void prep_kernel(
    const float* __restrict__ x, const float* __restrict__ uu,
    const float* __restrict__ vv, u16t* __restrict__ xhi, u16t* __restrict__ xlo,
    u16t* __restrict__ xT, float* __restrict__ xsum,
    float* __restrict__ a, float* __restrict__ b)
{
  __shared__ float tile[64][65];
  const int s0 = blockIdx.x * 64;
  const int d0 = blockIdx.y * 64;
  const int t = threadIdx.x;
  #pragma unroll
  for (int p = 0; p < 4; ++p) {
    int r = (t >> 4) + p * 16;
    int c = (t & 15) * 4;
    float4 vf = *(const float4*)(x + (size_t)(s0 + r) * D + d0 + c);
    float f[4] = {vf.x, vf.y, vf.z, vf.w};
    tile[r][c+0] = vf.x; tile[r][c+1] = vf.y; tile[r][c+2] = vf.z; tile[r][c+3] = vf.w;
    ushort4v h, l;
    #pragma unroll
    for (int e = 0; e < 4; ++e) {
      unsigned int hb = f2bf_rn(f[e]);
      float hf = __uint_as_float(hb << 16);
      h[e] = (u16t)hb;
      l[e] = (u16t)f2bf_rn(f[e] - hf);
    }
    size_t idx = (size_t)(s0 + r) * D + d0 + c;
    *(ushort4v*)(xhi + idx) = h;
    *(ushort4v*)(xlo + idx) = l;
  }
  __syncthreads();
  // transpose write
  #pragma unroll
  for (int p = 0; p < 4; ++p) {
    int dd = (t >> 4) + p * 16;
    int ss = (t & 15) * 4;
    ushort4v o;
    #pragma unroll
    for (int e = 0; e < 4; ++e) o[e] = (u16t)f2bf_rn(tile[ss + e][dd]);
    *(ushort4v*)(xT + (size_t)(d0 + dd) * S + s0 + ss) = o;
  }
  // reductions
  if (t < 64) {               // column sums -> xsum[d0+t]
    float s = 0.f;
    #pragma unroll 8
    for (int r = 0; r < 64; ++r) s += tile[r][t];
    atomicAdd(&xsum[d0 + t], s);
  } else if (t < 128) {       // a rows
    int r = t - 64;
    float s = 0.f;
    for (int c = 0; c < 64; ++c) s += tile[r][c] * (uu[d0 + c] + uu[D + d0 + c]);
    atomicAdd(&a[s0 + r], s);
  } else if (t < 192) {       // b rows
    int r = t - 128;
    float s = 0.f;
    for (int c = 0; c < 64; ++c) s += tile[r][c] * (vv[d0 + c] + vv[D + d0 + c]);
    atomicAdd(&b[s0 + r], s);
  }
}

// ---------------------------------------------------------------------------
// M[i][j] = sum_n Wq[n][i]Wk[n][j]; hi/lo 3-term.  32x32x16, 1 frag/wave.
// ---------------------------------------------------------------------------
__global__ __launch_bounds__(256) void m_kernel(
    const u16t* __restrict__ wqth, const u16t* __restrict__ wqtl,
    const u16t* __restrict__ wkth, const u16t* __restrict__ wktl,
    u16t* __restrict__ mh, u16t* __restrict__ ml)
{
  __shared__ __align__(16) u16t Mbuf[4][64 * BK];  // 0:Ah 1:Al 2:Bh 3:Bl

  const int tid  = threadIdx.x;
  const int lane = tid & 63;
  const int wv   = tid >> 6;
  const int i0   = blockIdx.x * 64;
  const int j0   = blockIdx.y * 64;

  floatx16 acc = {};
  const int m0w = (wv & 1) * 32;
  const int n0w = (wv >> 1) * 32;
  const int srow = lane >> 2;
  const int scolw = ((lane & 3) ^ ((lane >> 3) & 3)) * 8;
  const int rsw = (lane >> 1) & 3;
  const int l31 = lane & 31;
  const int khi = lane >> 5;

  for (int k0 = 0; k0 < D; k0 += BK) {
    __syncthreads();
    {
      const u16t* src = (wv == 0) ? wqth : (wv == 1) ? wqtl : (wv == 2) ? wkth : wktl;
      const int base  = (wv < 2) ? i0 : j0;
      #pragma unroll
      for (int sg = 0; sg < 4; ++sg) {
        int row = base + sg * 16 + srow;
        size_t g = (size_t)row * D + k0 + scolw;
        GLDS(src + g, &Mbuf[wv][sg * 512]);
      }
    }
    __syncthreads();
    #pragma unroll
    for (int ks = 0; ks < 2; ++ks) {
      int slot = ((ks * 2 + khi) ^ rsw) * 8;
      int ar = (m0w + l31) * BK + slot;
      int br = (n0w + l31) * BK + slot;
      short8 ah = *(const short8*)&Mbuf[0][ar];
      short8 al = *(const short8*)&Mbuf[1][ar];
      short8 bh = *(const short8*)&Mbuf[2][br];
      short8 bl = *(const short8*)&Mbuf[3][br];
      acc = __builtin_amdgcn_mfma_f32_32x32x16_bf16(ah, bh, acc, 0, 0, 0);
      acc = __builtin_amdgcn_mfma_f32_32x32x16_bf16(ah, bl, acc, 0, 0, 0);
      acc = __builtin_amdgcn_mfma_f32_32x32x16_bf16(al, bh, acc, 0, 0, 0);
    }
  }
  {
    int j = j0 + n0w + l31;
    int ib = i0 + m0w + 4 * khi;
    #pragma unroll
    for (int r = 0; r < 16; ++r) {
      int i = ib + (r & 3) + 8 * (r >> 2);
      float f = acc[r];
      unsigned int hb = f2bf_rn(f);
      float hf = __uint_as_float(hb << 16);
      size_t idx = (size_t)i * D + j;
      mh[idx] = (u16t)hb;
      ml[idx] = (u16t)f2bf_rn(f - hf);
    }
  }
}

// ---------------------------------------------------------------------------
// Y[s][i] = sum_j x[s][j]*M[i][j]; hi/lo 3-term. BK=64 two-half staging,
// swizzled LDS, 32x32x16 MFMA (2x2 frags/wave). 128x128 tile, 256 thr.
// ---------------------------------------------------------------------------
__global__ __launch_bounds__(256) void y_kernel(
    const u16t* __restrict__ xhi, const u16t* __restrict__ xlo,
    const u16t* __restrict__ mhp, const u16t* __restrict__ mlp,
    u16t* __restrict__ yh, u16t* __restrict__ yl)
{
  __shared__ __align__(16) u16t Ah[2 * 128 * BK];
  __shared__ __align__(16) u16t Al[2 * 128 * BK];
  __shared__ __align__(16) u16t Bh[2 * 128 * BK];
  __shared__ __align__(16) u16t Bl[2 * 128 * BK];

  const int tid  = threadIdx.x;
  const int lane = tid & 63;
  const int wv   = tid >> 6;
  const int s0   = blockIdx.x * 128;
  const int i0   = blockIdx.y * 128;

  floatx16 acc[2][2] = {};
  const int m0w  = (wv & 1) * 64;
  const int n0w  = (wv >> 1) * 64;
  const int srow = lane >> 2;
  const int scolw = ((lane & 3) ^ ((lane >> 3) & 3)) * 8;
  const int rsw = (lane >> 1) & 3;
  const int l31 = lane & 31;
  const int khi = lane >> 5;

  for (int k0 = 0; k0 < D; k0 += 64) {
    __syncthreads();
    #pragma unroll
    for (int h = 0; h < 2; ++h) {
      #pragma unroll
      for (int sg = 0; sg < 2; ++sg) {
        int seg  = wv * 2 + sg;
        int arow = s0 + seg * 16 + srow;
        int brow = i0 + seg * 16 + srow;
        size_t ga = (size_t)arow * D + k0 + h * 32 + scolw;
        size_t gb = (size_t)brow * D + k0 + h * 32 + scolw;
        int lb = h * 4096 + seg * 512;
        GLDS(xhi + ga, &Ah[lb]);
        GLDS(xlo + ga, &Al[lb]);
        GLDS(mhp + gb, &Bh[lb]);
        GLDS(mlp + gb, &Bl[lb]);
      }
    }
    __syncthreads();
    #pragma unroll
    for (int h = 0; h < 2; ++h) {
      #pragma unroll
      for (int ks = 0; ks < 2; ++ks) {
        int slot = ((ks * 2 + khi) ^ rsw) * 8;
        short8 ah[2], al[2], bh[2], bl[2];
        #pragma unroll
        for (int t = 0; t < 2; ++t) {
          int ar = h * 4096 + (m0w + t * 32 + l31) * BK + slot;
          int br = h * 4096 + (n0w + t * 32 + l31) * BK + slot;
          ah[t] = *(const short8*)&Ah[ar];
          al[t] = *(const short8*)&Al[ar];
          bh[t] = *(const short8*)&Bh[br];
          bl[t] = *(const short8*)&Bl[br];
        }
        #pragma unroll
        for (int mt = 0; mt < 2; ++mt)
          #pragma unroll
          for (int nt = 0; nt < 2; ++nt) {
            acc[mt][nt] = __builtin_amdgcn_mfma_f32_32x32x16_bf16(ah[mt], bh[nt], acc[mt][nt], 0, 0, 0);
            acc[mt][nt] = __builtin_amdgcn_mfma_f32_32x32x16_bf16(ah[mt], bl[nt], acc[mt][nt], 0, 0, 0);
            acc[mt][nt] = __builtin_amdgcn_mfma_f32_32x32x16_bf16(al[mt], bh[nt], acc[mt][nt], 0, 0, 0);
          }
      }
    }
  }
  #pragma unroll
  for (int mt = 0; mt < 2; ++mt)
    #pragma unroll
    for (int nt = 0; nt < 2; ++nt) {
      int i  = i0 + n0w + nt * 32 + l31;
      int sb = s0 + m0w + mt * 32 + 4 * khi;
      #pragma unroll
      for (int r = 0; r < 16; ++r) {
        int s = sb + (r & 3) + 8 * (r >> 2);
        float f = acc[mt][nt][r];
        unsigned int hb = f2bf_rn(f);
        float hf = __uint_as_float(hb << 16);
        size_t idx = (size_t)s * D + i;
        yh[idx] = (u16t)hb;
        yl[idx] = (u16t)f2bf_rn(f - hf);
      }
    }
}

// ---------------------------------------------------------------------------
// Banded scores, 64x64 tiles: band[t][j] = x_t.Y_s + a[t] + b[s] + c
// 32x32x16 MFMA, 1 frag/wave.
// ---------------------------------------------------------------------------
__global__ __launch_bounds__(256) void scores_kernel(
    const u16t* __restrict__ xhi, const u16t* __restrict__ xlo,
    const u16t* __restrict__ yh, const u16t* __restrict__ yl,
    const float* __restrict__ a, const float* __restrict__ b,
    const float* __restrict__ cbuf, float* __restrict__ band)
{
  __shared__ __align__(16) u16t Ah[2 * 64 * BK];
  __shared__ __align__(16) u16t Al[2 * 64 * BK];
  __shared__ __align__(16) u16t Bh[2 * 64 * BK];
  __shared__ __align__(16) u16t Bl[2 * 64 * BK];

  const int tid  = threadIdx.x;
  const int lane = tid & 63;
  const int wv   = tid >> 6;
  const int t0   = blockIdx.x * 64;
  const int jt   = blockIdx.y;              // 0..4
  const int s_base = t0 - 128 + jt * 64;
  const float cval = cbuf[0];

  floatx16 acc = {};
  const int m0w  = (wv & 1) * 32;
  const int n0w  = (wv >> 1) * 32;
  const int srow = lane >> 2;
  const int scolw = ((lane & 3) ^ ((lane >> 3) & 3)) * 8;
  const int rsw = (lane >> 1) & 3;
  const int l31 = lane & 31;
  const int khi = lane >> 5;

  for (int k0 = 0; k0 < D; k0 += 64) {
    __syncthreads();
    #pragma unroll
    for (int h = 0; h < 2; ++h) {
      int arow = t0 + wv * 16 + srow;
      int brow = s_base + wv * 16 + srow;
      brow = min(max(brow, 0), S - 1);
      size_t ga = (size_t)arow * D + k0 + h * 32 + scolw;
      size_t gb = (size_t)brow * D + k0 + h * 32 + scolw;
      int lb = h * 2048 + wv * 512;
      GLDS(xhi + ga, &Ah[lb]);
      GLDS(xlo + ga, &Al[lb]);
      GLDS(yh + gb, &Bh[lb]);
      GLDS(yl + gb, &Bl[lb]);
    }
    __syncthreads();
    #pragma unroll
    for (int h = 0; h < 2; ++h) {
      #pragma unroll
      for (int ks = 0; ks < 2; ++ks) {
        int slot = ((ks * 2 + khi) ^ rsw) * 8;
        int ar = h * 2048 + (m0w + l31) * BK + slot;
        int br = h * 2048 + (n0w + l31) * BK + slot;
        short8 ah = *(const short8*)&Ah[ar];
        short8 al = *(const short8*)&Al[ar];
        short8 bh = *(const short8*)&Bh[br];
        short8 bl = *(const short8*)&Bl[br];
        acc = __builtin_amdgcn_mfma_f32_32x32x16_bf16(ah, bh, acc, 0, 0, 0);
        acc = __builtin_amdgcn_mfma_f32_32x32x16_bf16(ah, bl, acc, 0, 0, 0);
        acc = __builtin_amdgcn_mfma_f32_32x32x16_bf16(al, bh, acc, 0, 0, 0);
      }
    }
  }
  {
    int n_loc = n0w + l31;
    int s = s_base + n_loc;
    float bv = (s >= 0 && s < S) ? b[s] : 0.f;
    int mb = m0w + 4 * khi;
    #pragma unroll
    for (int r = 0; r < 16; ++r) {
      int m_loc = mb + (r & 3) + 8 * (r >> 2);
      int t = t0 + m_loc;
      bool inwin = (s >= t - WINDOW) && (s < t + WINDOW) && (s >= 0) && (s < S);
      float sv = inwin ? (acc[r] + a[t] + bv + cval) : 0.f;
      band[(size_t)t * BAND + jt * 64 + n_loc] = sv;
    }
  }
}

// ---------------------------------------------------------------------------
// Softmax over band (320); P = (e - e0)*dinv as bf16; e0d = e0*dinv.
// ---------------------------------------------------------------------------
__global__ __launch_bounds__(256) void softmax_kernel(
    const float* __restrict__ band, u16t* __restrict__ Pb, float* __restrict__ e0d)
{
  const int lane = threadIdx.x & 63;
  const int w    = threadIdx.x >> 6;
  const int t    = blockIdx.x * 4 + w;
  const float* row = band + (size_t)t * BAND;
  float v[5];
  float mx = 0.f;
  #pragma unroll
  for (int i = 0; i < 5; ++i) {
    v[i] = row[i * 64 + lane];
    mx = fmaxf(mx, v[i]);
  }
  mx = wave_max(mx);
  float e0 = __expf(-mx);
  float ss = 0.f;
  #pragma unroll
  for (int i = 0; i < 5; ++i) {
    v[i] = __expf(v[i] - mx);
    ss += v[i];
  }
  ss = wave_sum(ss);
  float dinv = 1.f / (ss + (float)(S - BAND) * e0);
  #pragma unroll
  for (int i = 0; i < 5; ++i)
    Pb[(size_t)t * BAND + i * 64 + lane] = (u16t)f2bf_rn((v[i] - e0) * dinv);
  if (lane == 0) e0d[t] = e0 * dinv;
}

// ---------------------------------------------------------------------------
// PV: out[t][d] = sum_j Pb[t][j]*x[origin+j][d] + e0d[t]*xsum[d].
// 64-row t-tiles, K=320, swizzled LDS, 32x32x16 MFMA (1x2 frags/wave).
// ---------------------------------------------------------------------------
__global__ __launch_bounds__(256) void pv_kernel(
    const u16t* __restrict__ Pb, const u16t* __restrict__ xT,
    const float* __restrict__ e0d, const float* __restrict__ xsum,
    float* __restrict__ out)
{
  __shared__ __align__(16) u16t Ab[2 * 64 * BK];
  __shared__ __align__(16) u16t Bb[2 * 128 * BK];

  const int tid  = threadIdx.x;
  const int lane = tid & 63;
  const int wv   = tid >> 6;
  const int t0   = blockIdx.x * 64;
  const int d0   = blockIdx.y * 128;
  const int origin = t0 - 128;

  floatx16 acc[2] = {};
  const int m0w  = (wv & 1) * 32;   // t rows within tile
  const int n0w  = (wv >> 1) * 64;  // d cols within tile
  const int srow = lane >> 2;
  const int scolw = ((lane & 3) ^ ((lane >> 3) & 3)) * 8;
  const int rsw = (lane >> 1) & 3;
  const int l31 = lane & 31;
  const int khi = lane >> 5;

  for (int k0 = 0; k0 < BAND; k0 += 64) {
    __syncthreads();
    #pragma unroll
    for (int h = 0; h < 2; ++h) {
      {
        int arow = t0 + wv * 16 + srow;
        size_t ga = (size_t)arow * BAND + k0 + h * 32 + scolw;
        int lb = h * 2048 + wv * 512;
        GLDS(Pb + ga, &Ab[lb]);
      }
      #pragma unroll
      for (int sg = 0; sg < 2; ++sg) {
        int seg  = wv * 2 + sg;
        int brow = d0 + seg * 16 + srow;
        int s_g  = origin + k0 + h * 32 + scolw;
        s_g = min(max(s_g, 0), S - 8);
        size_t gb = (size_t)brow * S + s_g;
        int lb = h * 4096 + seg * 512;
        GLDS(xT + gb, &Bb[lb]);
      }
    }
    __syncthreads();
    #pragma unroll
    for (int h = 0; h < 2; ++h) {
      #pragma unroll
      for (int ks = 0; ks < 2; ++ks) {
        int slot = ((ks * 2 + khi) ^ rsw) * 8;
        short8 af = *(const short8*)&Ab[h * 2048 + (m0w + l31) * BK + slot];
        short8 bf[2];
        #pragma unroll
        for (int t = 0; t < 2; ++t)
          bf[t] = *(const short8*)&Bb[h * 4096 + (n0w + t * 32 + l31) * BK + slot];
        #pragma unroll
        for (int nt = 0; nt < 2; ++nt)
          acc[nt] = __builtin_amdgcn_mfma_f32_32x32x16_bf16(af, bf[nt], acc[nt], 0, 0, 0);
      }
    }
  }
  #pragma unroll
  for (int nt = 0; nt < 2; ++nt) {
    int n_g = d0 + n0w + nt * 32 + l31;
    float xs = xsum[n_g];
    int mb = t0 + m0w + 4 * khi;
    #pragma unroll
    for (int r = 0; r < 16; ++r) {
      int m_g = mb + (r & 3) + 8 * (r >> 2);
      out[(size_t)m_g * D + n_g] = acc[nt][r] + e0d[m_g] * xs;
    }
  }
}

// ---------------------------------------------------------------------------
// Fallback path (small workspace): fp32 proj + VALU attn
// ---------------------------------------------------------------------------
__global__ __launch_bounds__(256) void proj_kernel(
    const float* __restrict__ x, const float* __restrict__ Wq,
    const float* __restrict__ bqv, const float* __restrict__ Wk,
    const float* __restrict__ bkv, float* __restrict__ qout,
    float* __restrict__ kout)
{
  __shared__ __align__(16) float xs[BK][PAD];
  __shared__ __align__(16) float wqs[BK][PAD];
  __shared__ __align__(16) float wks[BK][PAD];
  const int tid = threadIdx.x;
  const int tx = tid & 15, ty = tid >> 4;
  const int t0 = blockIdx.x * 64, i0 = blockIdx.y * 64;
  float accq[4][4] = {}, acck[4][4] = {};
  const int lrow0 = tid >> 3, lc4 = (tid & 7) * 4;
  for (int k0 = 0; k0 < D; k0 += BK) {
    __syncthreads();
    #pragma unroll
    for (int p = 0; p < 2; ++p) {
      int row = lrow0 + p * 32;
      float4 a = *(const float4*)(x  + (size_t)(t0 + row) * D + k0 + lc4);
      float4 b = *(const float4*)(Wq + (size_t)(i0 + row) * D + k0 + lc4);
      float4 c = *(const float4*)(Wk + (size_t)(i0 + row) * D + k0 + lc4);
      xs [lc4+0][row]=a.x; xs [lc4+1][row]=a.y; xs [lc4+2][row]=a.z; xs [lc4+3][row]=a.w;
      wqs[lc4+0][row]=b.x; wqs[lc4+1][row]=b.y; wqs[lc4+2][row]=b.z; wqs[lc4+3][row]=b.w;
      wks[lc4+0][row]=c.x; wks[lc4+1][row]=c.y; wks[lc4+2][row]=c.z; wks[lc4+3][row]=c.w;
    }
    __syncthreads();
    #pragma unroll
    for (int kk = 0; kk < BK; ++kk) {
      float4 av = *(const float4*)&xs [kk][ty*4];
      float4 bv = *(const float4*)&wqs[kk][tx*4];
      float4 cv = *(const float4*)&wks[kk][tx*4];
      float a[4] = {av.x, av.y, av.z, av.w};
      float b[4] = {bv.x, bv.y, bv.z, bv.w};
      float c[4] = {cv.x, cv.y, cv.z, cv.w};
      #pragma unroll
      for (int r = 0; r < 4; ++r)
        #pragma unroll
        for (int cc = 0; cc < 4; ++cc) {
          accq[r][cc] = fmaf(a[r], b[cc], accq[r][cc]);
          acck[r][cc] = fmaf(a[r], c[cc], acck[r][cc]);
        }
    }
  }
  float4 bq4 = *(const float4*)(bqv + i0 + tx*4);
  float4 bk4 = *(const float4*)(bkv + i0 + tx*4);
  #pragma unroll
  for (int r = 0; r < 4; ++r) {
    int trow = t0 + ty*4 + r;
    float4 oq = { accq[r][0]+bq4.x, accq[r][1]+bq4.y, accq[r][2]+bq4.z, accq[r][3]+bq4.w };
    float4 ok = { acck[r][0]+bk4.x, acck[r][1]+bk4.y, acck[r][2]+bk4.z, acck[r][3]+bk4.w };
    *(float4*)(qout + (size_t)trow * D + i0 + tx*4) = oq;
    *(float4*)(kout + (size_t)trow * D + i0 + tx*4) = ok;
  }
}

__global__ __launch_bounds__(256) void colsum_kernel(const float* __restrict__ x,
                                                     float* __restrict__ xsum)
{
  int d = blockIdx.x * 256 + threadIdx.x;
  int tbase = blockIdx.y * 256;
  float s = 0.f;
  for (int t = 0; t < 256; ++t) s += x[(size_t)(tbase + t) * D + d];
  atomicAdd(&xsum[d], s);
}

__global__ __launch_bounds__(256) void attn_kernel(
    const float* __restrict__ x, const float* __restrict__ q,
    const float* __restrict__ kmat, const float* __restrict__ xsum,
    float* __restrict__ out)
{
  __shared__ __align__(16) float scl[TQ][UMAX];
  __shared__ float e0s[TQ], dinv[TQ];
  const int tid = threadIdx.x, lane = tid & 63, wv = tid >> 6;
  const int t0 = blockIdx.x * TQ;
  const int lo_u = max(0, t0 - WINDOW);
  const int hi_u = min(S, t0 + TQ - 1 + WINDOW);
  const int ucnt = hi_u - lo_u;
  for (int i = tid; i < TQ * UMAX; i += 256) (&scl[0][0])[i] = 0.f;
  __syncthreads();
  {
    const int tiB = wv * 4;
    float4 qf[4][4];
    #pragma unroll
    for (int g = 0; g < 4; ++g) {
      int t = t0 + tiB + g;
      #pragma unroll
      for (int j = 0; j < 4; ++j)
        qf[g][j] = *(const float4*)(q + (size_t)t * D + lane*4 + j*256);
    }
    const int wlo = max(0, t0 + tiB - WINDOW);
    const int whi = min(S, t0 + tiB + 3 + WINDOW);
    for (int s = wlo; s < whi; ++s) {
      float4 kf[4];
      #pragma unroll
      for (int j = 0; j < 4; ++j)
        kf[j] = *(const float4*)(kmat + (size_t)s * D + lane*4 + j*256);
      float acc[4];
      #pragma unroll
      for (int g = 0; g < 4; ++g) {
        float v = 0.f;
        #pragma unroll
        for (int j = 0; j < 4; ++j) {
          v = fmaf(qf[g][j].x, kf[j].x, v);
          v = fmaf(qf[g][j].y, kf[j].y, v);
          v = fmaf(qf[g][j].z, kf[j].z, v);
          v = fmaf(qf[g][j].w, kf[j].w, v);
        }
        acc[g] = v;
      }
      #pragma unroll
      for (int g = 0; g < 4; ++g) {
        float tot = wave_sum(acc[g]);
        int t = t0 + tiB + g;
        if (lane == 0 && s >= t - WINDOW && s < t + WINDOW)
          scl[tiB + g][s - lo_u] = tot;
      }
    }
  }
  __syncthreads();
  #pragma unroll
  for (int g = 0; g < 4; ++g) {
    int ti = wv * 4 + g;
    int t = t0 + ti;
    int lo = max(0, t - WINDOW), hi = min(S, t + WINDOW);
    int cnt = hi - lo, off = lo - lo_u;
    float m = 0.f;
    for (int i = lane; i < cnt; i += 64) m = fmaxf(m, scl[ti][off + i]);
    m = wave_max(m);
    float e0 = __expf(-m);
    float ssum = 0.f;
    for (int i = lane; i < cnt; i += 64) {
      float e = __expf(scl[ti][off + i] - m);
      ssum += e;
      scl[ti][off + i] = e - e0;
    }
    ssum = wave_sum(ssum);
    if (lane == 0) {
      dinv[ti] = 1.f / (ssum + (float)(S - cnt) * e0);
      e0s[ti] = e0;
    }
  }
  __syncthreads();
  {
    const int c4 = tid * 4;
    float4 acc[TQ];
    #pragma unroll
    for (int ti = 0; ti < TQ; ++ti) acc[ti] = make_float4(0.f, 0.f, 0.f, 0.f);
    for (int su = 0; su < ucnt; su += 4) {
      float4 xr[4];
      #pragma unroll
      for (int u = 0; u < 4; ++u)
        xr[u] = *(const float4*)(x + (size_t)(lo_u + su + u) * D + c4);
      #pragma unroll
      for (int ti = 0; ti < TQ; ++ti) {
        float4 w4 = *(const float4*)&scl[ti][su];
        float wvv[4] = {w4.x, w4.y, w4.z, w4.w};
        #pragma unroll
        for (int u = 0; u < 4; ++u) {
          acc[ti].x = fmaf(wvv[u], xr[u].x, acc[ti].x);
          acc[ti].y = fmaf(wvv[u], xr[u].y, acc[ti].y);
          acc[ti].z = fmaf(wvv[u], xr[u].z, acc[ti].z);
          acc[ti].w = fmaf(wvv[u], xr[u].w, acc[ti].w);
        }
      }
    }
    float4 xsv = *(const float4*)(xsum + c4);
    #pragma unroll
    for (int ti = 0; ti < TQ; ++ti) {
      float e0 = e0s[ti], di = dinv[ti];
      float4 o;
      o.x = (acc[ti].x + e0 * xsv.x) * di;
      o.y = (acc[ti].y + e0 * xsv.y) * di;
      o.z = (acc[ti].z + e0 * xsv.z) * di;
      o.w = (acc[ti].w + e0 * xsv.w) * di;
      *(float4*)(out + (size_t)(t0 + ti) * D + c4) = o;
    }
  }
}

extern "C" void kernel_launch(void* const* d_in, const int* in_sizes, int n_in,
                              void* d_out, int out_size, void* d_ws, size_t ws_size,
                              hipStream_t stream) {
  const float* x  = (const float*)d_in[0];
  const float* Wq = (const float*)d_in[1];
  const float* bq = (const float*)d_in[2];
  const float* Wk = (const float*)d_in[3];
  const float* bk = (const float*)d_in[4];
  float* outp = (float*)d_out;

  const size_t SD = (size_t)S * D;
  const size_t DD = (size_t)D * D;

  // fp32 scalar region: [xsum D][a S][b S] (zeroed in wuv) [uu 2D][vv 2D][cbuf 16]
  float* xsum = (float*)d_ws;            // D
  float* a    = xsum + D;                // S
  float* b    = a + S;                   // S
  float* uu   = b + S;                   // 2D (two n-slices)
  float* vv   = uu + 2 * D;              // 2D
  float* cbuf = vv + 2 * D;              // 16

  u16t* xhi  = (u16t*)(cbuf + 16);
  u16t* xlo  = xhi + SD;
  u16t* xT   = xlo + SD;
  u16t* wqth = xT + SD;
  u16t* wqtl = wqth + DD;
  u16t* wkth = wqtl + DD;
  u16t* wktl = wkth + DD;
  u16t* mh   = wktl + DD;
  u16t* ml   = mh + DD;
  u16t* yh   = ml + DD;
  u16t* yl   = yh + SD;
  float* band = (float*)(yl + SD);                // S*BAND f32
  u16t*  Pb   = (u16t*)(band + (size_t)S * BAND); // S*BAND u16
  float* e0d  = (float*)(Pb + (size_t)S * BAND);  // S f32
  size_t needed = (size_t)((char*)(e0d + S) - (char*)d_ws);

  if (ws_size >= needed) {
    wuv_kernel<<<dim3(16, 16, 3), 256, 0, stream>>>(
        Wq, Wk, bq, bk, uu, vv, cbuf, wqth, wqtl, wkth, wktl, xsum);
    prep_kernel<<<dim3(S / 64, D / 64), 256, 0, stream>>>(x, uu, vv, xhi, xlo, xT, xsum, a, b);
    m_kernel<<<dim3(D / 64, D / 64), 256, 0, stream>>>(wqth, wqtl, wkth, wktl, mh, ml);
    y_kernel<<<dim3(S / 128, D / 128), 256, 0, stream>>>(xhi, xlo, mh, ml, yh, yl);
    scores_kernel<<<dim3(S / 64, 5), 256, 0, stream>>>(xhi, xlo, yh, yl, a, b, cbuf, band);
    softmax_kernel<<<S / 4, 256, 0, stream>>>(band, Pb, e0d);
    pv_kernel<<<dim3(S / 64, D / 128), 256, 0, stream>>>(Pb, xT, e0d, xsum, outp);
  } else {
    float* xs2  = (float*)d_ws;
    float* q    = xs2 + D;
    float* kbuf = q + SD;
    (void)hipMemsetAsync(xs2, 0, D * sizeof(float), stream);
    colsum_kernel<<<dim3(D / 256, S / 256), 256, 0, stream>>>(x, xs2);
    proj_kernel<<<dim3(S / 64, D / 64), 256, 0, stream>>>(x, Wq, bq, Wk, bk, q, kbuf);
    attn_kernel<<<S / TQ, 256, 0, stream>>>(x, q, kbuf, xs2, outp);
  }
}

// Round 7
// 288.024 us; speedup vs baseline: 2.2257x; 1.0057x over previous
//
#include <hip/hip_runtime.h>

#define S 8192
#define D 1024
#define WINDOW 128
#define TQ 16
#define UMAX 288
#define BK 32
#define PAD 68
#define BAND 320   // band width: s in [t_tile64-128, t_tile64+192)

typedef __attribute__((ext_vector_type(8))) short short8;
typedef __attribute__((ext_vector_type(4))) float floatx4;
typedef __attribute__((ext_vector_type(4))) unsigned short ushort4v;
typedef unsigned short u16t;

__device__ __forceinline__ float wave_sum(float v) {
  #pragma unroll
  for (int off = 32; off > 0; off >>= 1) v += __shfl_xor(v, off, 64);
  return v;
}
__device__ __forceinline__ float wave_max(float v) {
  #pragma unroll
  for (int off = 32; off > 0; off >>= 1) v = fmaxf(v, __shfl_xor(v, off, 64));
  return v;
}
__device__ __forceinline__ unsigned int f2bf_rn(float f) {
  unsigned int u = __float_as_uint(f);
  return (u + 0x7fffu + ((u >> 16) & 1u)) >> 16;
}

#define GLDS(gp, lp) __builtin_amdgcn_global_load_lds( \
    (const __attribute__((address_space(1))) void*)(gp), \
    (__attribute__((address_space(3))) void*)(lp), 16, 0, 0)

// LDS bank-conflict-free addressing for [row][32 u16] buffers staged via
// global_load_lds (linear dest).  Source col-chunk is pre-swizzled so the
// 16x16 frag read (16-lane, 64B row stride) lands on distinct bank groups.
//   staging: thread loads global chunk ((lane&3) ^ ((lane>>3)&3))
//   read:    wanted chunk q=(lane>>4) lives at slot q ^ ((lane>>1)&3)
// (verified round 1: SQ_LDS_BANK_CONFLICT 4.19M -> 0)

// ---------------------------------------------------------------------------
// Merged W-prep dispatch (no memset node):
//  z=0: transpose Wq -> wqth/wqtl     z=1: transpose Wk -> wkth/wktl
//  z=2, by==0, bx<8 : uv direct (2 n-slices, no atomics)
//  z=2, by==0, bx==8: cbuf = bq.bk
//  z=2, by>=1       : zero xsum/a/b region (consumed only by NEXT dispatch)
// ---------------------------------------------------------------------------
__global__ __launch_bounds__(256) void wuv_kernel(
    const float* __restrict__ Wq, const float* __restrict__ Wk,
    const float* __restrict__ bq, const float* __restrict__ bk,
    float* __restrict__ uu, float* __restrict__ vv, float* __restrict__ cbuf,
    u16t* __restrict__ wqth, u16t* __restrict__ wqtl,
    u16t* __restrict__ wkth, u16t* __restrict__ wktl,
    float* __restrict__ zreg)
{
  __shared__ float tile[64][65];
  __shared__ float cr[4];
  const int t = threadIdx.x;
  if (blockIdx.z == 2) {
    if (blockIdx.y == 0) {
      if (blockIdx.x < 8) {          // uv: direct stores to slice nh
        const int i  = (blockIdx.x & 3) * 256 + t;
        const int nh = blockIdx.x >> 2;
        float us = 0.f, vs = 0.f;
        for (int n = nh * 512; n < nh * 512 + 512; ++n) {
          us += Wq[(size_t)n * D + i] * bk[n];
          vs += Wk[(size_t)n * D + i] * bq[n];
        }
        uu[(size_t)nh * D + i] = us;
        vv[(size_t)nh * D + i] = vs;
      } else if (blockIdx.x == 8) {  // cbuf
        float cs = 0.f;
        for (int n = t; n < D; n += 256) cs += bq[n] * bk[n];
        cs = wave_sum(cs);
        if ((t & 63) == 0) cr[t >> 6] = cs;
        __syncthreads();
        if (t == 0) cbuf[0] = cr[0] + cr[1] + cr[2] + cr[3];
      }
    } else {                         // zero xsum/a/b (D + 2S floats)
      int fb  = (blockIdx.y - 1) * 16 + blockIdx.x;  // 0..239
      int idx = fb * 256 + t;
      if (idx < D + 2 * S) zreg[idx] = 0.f;
    }
    return;
  }
  const float* W = blockIdx.z ? Wk : Wq;
  u16t* oh = blockIdx.z ? wkth : wqth;
  u16t* ol = blockIdx.z ? wktl : wqtl;
  const int n0 = blockIdx.x * 64;   // source row
  const int i0 = blockIdx.y * 64;   // source col
  #pragma unroll
  for (int p = 0; p < 4; ++p) {
    int r = (t >> 4) + p * 16;
    int c = (t & 15) * 4;
    float4 vf = *(const float4*)(W + (size_t)(n0 + r) * D + i0 + c);
    tile[r][c+0] = vf.x; tile[r][c+1] = vf.y; tile[r][c+2] = vf.z; tile[r][c+3] = vf.w;
  }
  __syncthreads();
  #pragma unroll
  for (int p = 0; p < 4; ++p) {
    int ii = (t >> 4) + p * 16;
    int nn = (t & 15) * 4;
    ushort4v h, l;
    #pragma unroll
    for (int e = 0; e < 4; ++e) {
      float f = tile[nn + e][ii];
      unsigned int hb = f2bf_rn(f);
      float hf = __uint_as_float(hb << 16);
      h[e] = (u16t)hb;
      l[e] = (u16t)f2bf_rn(f - hf);
    }
    size_t idx = (size_t)(i0 + ii) * D + n0 + nn;
    *(ushort4v*)(oh + idx) = h;
    *(ushort4v*)(ol + idx) = l;
  }
}

// ---------------------------------------------------------------------------
// prep: read x tile once -> xhi/xlo (split), xT (bf16 transpose),
//       xsum partials, a = x.u partials, b = x.v partials  (u = uu0+uu1)
// ---------------------------------------------------------------------------
__global__ __launch_bounds__(256) void prep_kernel(
    const float* __restrict__ x, const float* __restrict__ uu,
    const float* __restrict__ vv, u16t* __restrict__ xhi, u16t* __restrict__ xlo,
    u16t* __restrict__ xT, float* __restrict__ xsum,
    float* __restrict__ a, float* __restrict__ b)
{
  __shared__ float tile[64][65];
  const int s0 = blockIdx.x * 64;
  const int d0 = blockIdx.y * 64;
  const int t = threadIdx.x;
  #pragma unroll
  for (int p = 0; p < 4; ++p) {
    int r = (t >> 4) + p * 16;
    int c = (t & 15) * 4;
    float4 vf = *(const float4*)(x + (size_t)(s0 + r) * D + d0 + c);
    float f[4] = {vf.x, vf.y, vf.z, vf.w};
    tile[r][c+0] = vf.x; tile[r][c+1] = vf.y; tile[r][c+2] = vf.z; tile[r][c+3] = vf.w;
    ushort4v h, l;
    #pragma unroll
    for (int e = 0; e < 4; ++e) {
      unsigned int hb = f2bf_rn(f[e]);
      float hf = __uint_as_float(hb << 16);
      h[e] = (u16t)hb;
      l[e] = (u16t)f2bf_rn(f[e] - hf);
    }
    size_t idx = (size_t)(s0 + r) * D + d0 + c;
    *(ushort4v*)(xhi + idx) = h;
    *(ushort4v*)(xlo + idx) = l;
  }
  __syncthreads();
  // transpose write
  #pragma unroll
  for (int p = 0; p < 4; ++p) {
    int dd = (t >> 4) + p * 16;
    int ss = (t & 15) * 4;
    ushort4v o;
    #pragma unroll
    for (int e = 0; e < 4; ++e) o[e] = (u16t)f2bf_rn(tile[ss + e][dd]);
    *(ushort4v*)(xT + (size_t)(d0 + dd) * S + s0 + ss) = o;
  }
  // reductions
  if (t < 64) {               // column sums -> xsum[d0+t]
    float s = 0.f;
    #pragma unroll 8
    for (int r = 0; r < 64; ++r) s += tile[r][t];
    atomicAdd(&xsum[d0 + t], s);
  } else if (t < 128) {       // a rows
    int r = t - 64;
    float s = 0.f;
    for (int c = 0; c < 64; ++c) s += tile[r][c] * (uu[d0 + c] + uu[D + d0 + c]);
    atomicAdd(&a[s0 + r], s);
  } else if (t < 192) {       // b rows
    int r = t - 128;
    float s = 0.f;
    for (int c = 0; c < 64; ++c) s += tile[r][c] * (vv[d0 + c] + vv[D + d0 + c]);
    atomicAdd(&b[s0 + r], s);
  }
}

// ---------------------------------------------------------------------------
// M[i][j] = sum_n Wq[n][i]Wk[n][j]; hi/lo 3-term.  16x16x32, swizzled LDS.
// ---------------------------------------------------------------------------
__global__ __launch_bounds__(256) void m_kernel(
    const u16t* __restrict__ wqth, const u16t* __restrict__ wqtl,
    const u16t* __restrict__ wkth, const u16t* __restrict__ wktl,
    u16t* __restrict__ mh, u16t* __restrict__ ml)
{
  __shared__ __align__(16) u16t Mbuf[4][64 * BK];  // 0:Ah 1:Al 2:Bh 3:Bl

  const int tid  = threadIdx.x;
  const int lane = tid & 63;
  const int wv   = tid >> 6;
  const int i0   = blockIdx.x * 64;
  const int j0   = blockIdx.y * 64;

  floatx4 acc[2][2] = {};
  const int m0w = (wv & 1) * 32;
  const int n0w = (wv >> 1) * 32;
  const int srow = lane >> 2;
  const int scolw = ((lane & 3) ^ ((lane >> 3) & 3)) * 8;
  const int rs    = (((lane >> 4) ^ ((lane >> 1) & 3)) * 8);

  for (int k0 = 0; k0 < D; k0 += BK) {
    __syncthreads();
    {
      const u16t* src = (wv == 0) ? wqth : (wv == 1) ? wqtl : (wv == 2) ? wkth : wktl;
      const int base  = (wv < 2) ? i0 : j0;
      #pragma unroll
      for (int sg = 0; sg < 4; ++sg) {
        int row = base + sg * 16 + srow;
        size_t g = (size_t)row * D + k0 + scolw;
        GLDS(src + g, &Mbuf[wv][sg * 512]);
      }
    }
    __syncthreads();
    short8 ah[2], al[2], bh[2], bl[2];
    #pragma unroll
    for (int t = 0; t < 2; ++t) {
      int ar = (m0w + t * 16 + (lane & 15)) * BK + rs;
      int br = (n0w + t * 16 + (lane & 15)) * BK + rs;
      ah[t] = *(const short8*)&Mbuf[0][ar];
      al[t] = *(const short8*)&Mbuf[1][ar];
      bh[t] = *(const short8*)&Mbuf[2][br];
      bl[t] = *(const short8*)&Mbuf[3][br];
    }
    #pragma unroll
    for (int mt = 0; mt < 2; ++mt)
      #pragma unroll
      for (int nt = 0; nt < 2; ++nt) {
        acc[mt][nt] = __builtin_amdgcn_mfma_f32_16x16x32_bf16(ah[mt], bh[nt], acc[mt][nt], 0, 0, 0);
        acc[mt][nt] = __builtin_amdgcn_mfma_f32_16x16x32_bf16(ah[mt], bl[nt], acc[mt][nt], 0, 0, 0);
        acc[mt][nt] = __builtin_amdgcn_mfma_f32_16x16x32_bf16(al[mt], bh[nt], acc[mt][nt], 0, 0, 0);
      }
  }
  #pragma unroll
  for (int mt = 0; mt < 2; ++mt)
    #pragma unroll
    for (int nt = 0; nt < 2; ++nt) {
      int j = j0 + n0w + nt * 16 + (lane & 15);
      int i = i0 + m0w + mt * 16 + (lane >> 4) * 4;
      #pragma unroll
      for (int r = 0; r < 4; ++r) {
        float f = acc[mt][nt][r];
        unsigned int hb = f2bf_rn(f);
        float hf = __uint_as_float(hb << 16);
        size_t idx = (size_t)(i + r) * D + j;
        mh[idx] = (u16t)hb;
        ml[idx] = (u16t)f2bf_rn(f - hf);
      }
    }
}

// ---------------------------------------------------------------------------
// Y[s][i] = sum_j x[s][j]*M[i][j]; hi/lo 3-term. BK=64 two-half staging,
// swizzled LDS, 16x16x32 (verified 53.6us / conflicts 0).  XCD-swizzled
// grid: 512 blocks % 8 == 0 -> bijective; each XCD gets one M column-panel
// (512 KB, fits 4 MB XCD L2).
// ---------------------------------------------------------------------------
__global__ __launch_bounds__(256) void y_kernel(
    const u16t* __restrict__ xhi, const u16t* __restrict__ xlo,
    const u16t* __restrict__ mhp, const u16t* __restrict__ mlp,
    u16t* __restrict__ yh, u16t* __restrict__ yl)
{
  __shared__ __align__(16) u16t Ah[2 * 128 * BK];
  __shared__ __align__(16) u16t Al[2 * 128 * BK];
  __shared__ __align__(16) u16t Bh[2 * 128 * BK];
  __shared__ __align__(16) u16t Bl[2 * 128 * BK];

  const int tid  = threadIdx.x;
  const int lane = tid & 63;
  const int wv   = tid >> 6;
  // XCD-aware bijective swizzle (nwg = 64*8 = 512, 512/8 = 64 per XCD)
  const int bid  = blockIdx.y * gridDim.x + blockIdx.x;
  const int sw   = (bid & 7) * 64 + (bid >> 3);
  const int s0   = (sw & 63) * 128;
  const int i0   = (sw >> 6) * 128;

  floatx4 acc[4][4] = {};
  const int m0w  = (wv & 1) * 64;
  const int n0w  = (wv >> 1) * 64;
  const int srow = lane >> 2;
  const int scolw = ((lane & 3) ^ ((lane >> 3) & 3)) * 8;
  const int rs    = (((lane >> 4) ^ ((lane >> 1) & 3)) * 8);

  for (int k0 = 0; k0 < D; k0 += 64) {
    __syncthreads();
    #pragma unroll
    for (int h = 0; h < 2; ++h) {
      #pragma unroll
      for (int sg = 0; sg < 2; ++sg) {
        int seg  = wv * 2 + sg;
        int arow = s0 + seg * 16 + srow;
        int brow = i0 + seg * 16 + srow;
        size_t ga = (size_t)arow * D + k0 + h * 32 + scolw;
        size_t gb = (size_t)brow * D + k0 + h * 32 + scolw;
        int lb = h * 4096 + seg * 512;
        GLDS(xhi + ga, &Ah[lb]);
        GLDS(xlo + ga, &Al[lb]);
        GLDS(mhp + gb, &Bh[lb]);
        GLDS(mlp + gb, &Bl[lb]);
      }
    }
    __syncthreads();
    #pragma unroll
    for (int h = 0; h < 2; ++h) {
      short8 ah[4], al[4], bh[4], bl[4];
      #pragma unroll
      for (int t = 0; t < 4; ++t) {
        int ar = h * 4096 + (m0w + t * 16 + (lane & 15)) * BK + rs;
        int br = h * 4096 + (n0w + t * 16 + (lane & 15)) * BK + rs;
        ah[t] = *(const short8*)&Ah[ar];
        al[t] = *(const short8*)&Al[ar];
        bh[t] = *(const short8*)&Bh[br];
        bl[t] = *(const short8*)&Bl[br];
      }
      #pragma unroll
      for (int mt = 0; mt < 4; ++mt)
        #pragma unroll
        for (int nt = 0; nt < 4; ++nt) {
          acc[mt][nt] = __builtin_amdgcn_mfma_f32_16x16x32_bf16(ah[mt], bh[nt], acc[mt][nt], 0, 0, 0);
          acc[mt][nt] = __builtin_amdgcn_mfma_f32_16x16x32_bf16(ah[mt], bl[nt], acc[mt][nt], 0, 0, 0);
          acc[mt][nt] = __builtin_amdgcn_mfma_f32_16x16x32_bf16(al[mt], bh[nt], acc[mt][nt], 0, 0, 0);
        }
    }
  }
  #pragma unroll
  for (int mt = 0; mt < 4; ++mt)
    #pragma unroll
    for (int nt = 0; nt < 4; ++nt) {
      int i = i0 + n0w + nt * 16 + (lane & 15);
      int s = s0 + m0w + mt * 16 + (lane >> 4) * 4;
      #pragma unroll
      for (int r = 0; r < 4; ++r) {
        float f = acc[mt][nt][r];
        unsigned int hb = f2bf_rn(f);
        float hf = __uint_as_float(hb << 16);
        size_t idx = (size_t)(s + r) * D + i;
        yh[idx] = (u16t)hb;
        yl[idx] = (u16t)f2bf_rn(f - hf);
      }
    }
}

// ---------------------------------------------------------------------------
// Banded scores, 64x64 tiles: band[t][j] = x_t.Y_s + a[t] + b[s] + c
// (s = (t&~63) - 128 + j, j in [0,320)), hi/lo 3-term, swizzled LDS.
// ---------------------------------------------------------------------------
__global__ __launch_bounds__(256) void scores_kernel(
    const u16t* __restrict__ xhi, const u16t* __restrict__ xlo,
    const u16t* __restrict__ yh, const u16t* __restrict__ yl,
    const float* __restrict__ a, const float* __restrict__ b,
    const float* __restrict__ cbuf, float* __restrict__ band)
{
  __shared__ __align__(16) u16t Ah[2 * 64 * BK];
  __shared__ __align__(16) u16t Al[2 * 64 * BK];
  __shared__ __align__(16) u16t Bh[2 * 64 * BK];
  __shared__ __align__(16) u16t Bl[2 * 64 * BK];

  const int tid  = threadIdx.x;
  const int lane = tid & 63;
  const int wv   = tid >> 6;
  const int t0   = blockIdx.x * 64;
  const int jt   = blockIdx.y;              // 0..4
  const int s_base = t0 - 128 + jt * 64;
  const float cval = cbuf[0];

  floatx4 acc[2][2] = {};
  const int m0w  = (wv & 1) * 32;
  const int n0w  = (wv >> 1) * 32;
  const int srow = lane >> 2;
  const int scolw = ((lane & 3) ^ ((lane >> 3) & 3)) * 8;
  const int rs    = (((lane >> 4) ^ ((lane >> 1) & 3)) * 8);

  for (int k0 = 0; k0 < D; k0 += 64) {
    __syncthreads();
    #pragma unroll
    for (int h = 0; h < 2; ++h) {
      int arow = t0 + wv * 16 + srow;
      int brow = s_base + wv * 16 + srow;
      brow = min(max(brow, 0), S - 1);
      size_t ga = (size_t)arow * D + k0 + h * 32 + scolw;
      size_t gb = (size_t)brow * D + k0 + h * 32 + scolw;
      int lb = h * 2048 + wv * 512;
      GLDS(xhi + ga, &Ah[lb]);
      GLDS(xlo + ga, &Al[lb]);
      GLDS(yh + gb, &Bh[lb]);
      GLDS(yl + gb, &Bl[lb]);
    }
    __syncthreads();
    #pragma unroll
    for (int h = 0; h < 2; ++h) {
      short8 ah[2], al[2], bh[2], bl[2];
      #pragma unroll
      for (int t = 0; t < 2; ++t) {
        int ar = h * 2048 + (m0w + t * 16 + (lane & 15)) * BK + rs;
        int br = h * 2048 + (n0w + t * 16 + (lane & 15)) * BK + rs;
        ah[t] = *(const short8*)&Ah[ar];
        al[t] = *(const short8*)&Al[ar];
        bh[t] = *(const short8*)&Bh[br];
        bl[t] = *(const short8*)&Bl[br];
      }
      #pragma unroll
      for (int mt = 0; mt < 2; ++mt)
        #pragma unroll
        for (int nt = 0; nt < 2; ++nt) {
          acc[mt][nt] = __builtin_amdgcn_mfma_f32_16x16x32_bf16(ah[mt], bh[nt], acc[mt][nt], 0, 0, 0);
          acc[mt][nt] = __builtin_amdgcn_mfma_f32_16x16x32_bf16(ah[mt], bl[nt], acc[mt][nt], 0, 0, 0);
          acc[mt][nt] = __builtin_amdgcn_mfma_f32_16x16x32_bf16(al[mt], bh[nt], acc[mt][nt], 0, 0, 0);
        }
    }
  }
  #pragma unroll
  for (int mt = 0; mt < 2; ++mt)
    #pragma unroll
    for (int nt = 0; nt < 2; ++nt) {
      int n_loc = n0w + nt * 16 + (lane & 15);
      int s = s_base + n_loc;
      float bv = (s >= 0 && s < S) ? b[s] : 0.f;
      #pragma unroll
      for (int r = 0; r < 4; ++r) {
        int m_loc = m0w + mt * 16 + (lane >> 4) * 4 + r;
        int t = t0 + m_loc;
        bool inwin = (s >= t - WINDOW) && (s < t + WINDOW) && (s >= 0) && (s < S);
        float sv = inwin ? (acc[mt][nt][r] + a[t] + bv + cval) : 0.f;
        band[(size_t)t * BAND + jt * 64 + n_loc] = sv;
      }
    }
}

// ---------------------------------------------------------------------------
// Softmax over band (320); P = (e - e0)*dinv as bf16; e0d = e0*dinv.
// ---------------------------------------------------------------------------
__global__ __launch_bounds__(256) void softmax_kernel(
    const float* __restrict__ band, u16t* __restrict__ Pb, float* __restrict__ e0d)
{
  const int lane = threadIdx.x & 63;
  const int w    = threadIdx.x >> 6;
  const int t    = blockIdx.x * 4 + w;
  const float* row = band + (size_t)t * BAND;
  float v[5];
  float mx = 0.f;
  #pragma unroll
  for (int i = 0; i < 5; ++i) {
    v[i] = row[i * 64 + lane];
    mx = fmaxf(mx, v[i]);
  }
  mx = wave_max(mx);
  float e0 = __expf(-mx);
  float ss = 0.f;
  #pragma unroll
  for (int i = 0; i < 5; ++i) {
    v[i] = __expf(v[i] - mx);
    ss += v[i];
  }
  ss = wave_sum(ss);
  float dinv = 1.f / (ss + (float)(S - BAND) * e0);
  #pragma unroll
  for (int i = 0; i < 5; ++i)
    Pb[(size_t)t * BAND + i * 64 + lane] = (u16t)f2bf_rn((v[i] - e0) * dinv);
  if (lane == 0) e0d[t] = e0 * dinv;
}

// ---------------------------------------------------------------------------
// PV: out[t][d] = sum_j Pb[t][j]*x[origin+j][d] + e0d[t]*xsum[d].
// 64-row t-tiles, K=320, swizzled LDS, 16x16x32.
// ---------------------------------------------------------------------------
__global__ __launch_bounds__(256) void pv_kernel(
    const u16t* __restrict__ Pb, const u16t* __restrict__ xT,
    const float* __restrict__ e0d, const float* __restrict__ xsum,
    float* __restrict__ out)
{
  __shared__ __align__(16) u16t Ab[2 * 64 * BK];
  __shared__ __align__(16) u16t Bb[2 * 128 * BK];

  const int tid  = threadIdx.x;
  const int lane = tid & 63;
  const int wv   = tid >> 6;
  const int t0   = blockIdx.x * 64;
  const int d0   = blockIdx.y * 128;
  const int origin = t0 - 128;

  floatx4 acc[2][4] = {};
  const int m0w  = (wv & 1) * 32;   // t rows within tile
  const int n0w  = (wv >> 1) * 64;  // d cols within tile
  const int srow = lane >> 2;
  const int scolw = ((lane & 3) ^ ((lane >> 3) & 3)) * 8;
  const int rs    = (((lane >> 4) ^ ((lane >> 1) & 3)) * 8);

  for (int k0 = 0; k0 < BAND; k0 += 64) {
    __syncthreads();
    #pragma unroll
    for (int h = 0; h < 2; ++h) {
      {
        int arow = t0 + wv * 16 + srow;
        size_t ga = (size_t)arow * BAND + k0 + h * 32 + scolw;
        int lb = h * 2048 + wv * 512;
        GLDS(Pb + ga, &Ab[lb]);
      }
      #pragma unroll
      for (int sg = 0; sg < 2; ++sg) {
        int seg  = wv * 2 + sg;
        int brow = d0 + seg * 16 + srow;
        int s_g  = origin + k0 + h * 32 + scolw;
        s_g = min(max(s_g, 0), S - 8);
        size_t gb = (size_t)brow * S + s_g;
        int lb = h * 4096 + seg * 512;
        GLDS(xT + gb, &Bb[lb]);
      }
    }
    __syncthreads();
    #pragma unroll
    for (int h = 0; h < 2; ++h) {
      short8 af[2], bf[4];
      #pragma unroll
      for (int t = 0; t < 2; ++t) {
        int ar = h * 2048 + (m0w + t * 16 + (lane & 15)) * BK + rs;
        af[t] = *(const short8*)&Ab[ar];
      }
      #pragma unroll
      for (int t = 0; t < 4; ++t) {
        int br = h * 4096 + (n0w + t * 16 + (lane & 15)) * BK + rs;
        bf[t] = *(const short8*)&Bb[br];
      }
      #pragma unroll
      for (int mt = 0; mt < 2; ++mt)
        #pragma unroll
        for (int nt = 0; nt < 4; ++nt)
          acc[mt][nt] = __builtin_amdgcn_mfma_f32_16x16x32_bf16(af[mt], bf[nt], acc[mt][nt], 0, 0, 0);
    }
  }
  #pragma unroll
  for (int mt = 0; mt < 2; ++mt)
    #pragma unroll
    for (int nt = 0; nt < 4; ++nt) {
      int n_g = d0 + n0w + nt * 16 + (lane & 15);
      float xs = xsum[n_g];
      #pragma unroll
      for (int r = 0; r < 4; ++r) {
        int m_g = t0 + m0w + mt * 16 + (lane >> 4) * 4 + r;
        out[(size_t)m_g * D + n_g] = acc[mt][nt][r] + e0d[m_g] * xs;
      }
    }
}

// ---------------------------------------------------------------------------
// Fallback path (small workspace): fp32 proj + VALU attn
// ---------------------------------------------------------------------------
__global__ __launch_bounds__(256) void proj_kernel(
    const float* __restrict__ x, const float* __restrict__ Wq,
    const float* __restrict__ bqv, const float* __restrict__ Wk,
    const float* __restrict__ bkv, float* __restrict__ qout,
    float* __restrict__ kout)
{
  __shared__ __align__(16) float xs[BK][PAD];
  __shared__ __align__(16) float wqs[BK][PAD];
  __shared__ __align__(16) float wks[BK][PAD];
  const int tid = threadIdx.x;
  const int tx = tid & 15, ty = tid >> 4;
  const int t0 = blockIdx.x * 64, i0 = blockIdx.y * 64;
  float accq[4][4] = {}, acck[4][4] = {};
  const int lrow0 = tid >> 3, lc4 = (tid & 7) * 4;
  for (int k0 = 0; k0 < D; k0 += BK) {
    __syncthreads();
    #pragma unroll
    for (int p = 0; p < 2; ++p) {
      int row = lrow0 + p * 32;
      float4 a = *(const float4*)(x  + (size_t)(t0 + row) * D + k0 + lc4);
      float4 b = *(const float4*)(Wq + (size_t)(i0 + row) * D + k0 + lc4);
      float4 c = *(const float4*)(Wk + (size_t)(i0 + row) * D + k0 + lc4);
      xs [lc4+0][row]=a.x; xs [lc4+1][row]=a.y; xs [lc4+2][row]=a.z; xs [lc4+3][row]=a.w;
      wqs[lc4+0][row]=b.x; wqs[lc4+1][row]=b.y; wqs[lc4+2][row]=b.z; wqs[lc4+3][row]=b.w;
      wks[lc4+0][row]=c.x; wks[lc4+1][row]=c.y; wks[lc4+2][row]=c.z; wks[lc4+3][row]=c.w;
    }
    __syncthreads();
    #pragma unroll
    for (int kk = 0; kk < BK; ++kk) {
      float4 av = *(const float4*)&xs [kk][ty*4];
      float4 bv = *(const float4*)&wqs[kk][tx*4];
      float4 cv = *(const float4*)&wks[kk][tx*4];
      float a[4] = {av.x, av.y, av.z, av.w};
      float b[4] = {bv.x, bv.y, bv.z, bv.w};
      float c[4] = {cv.x, cv.y, cv.z, cv.w};
      #pragma unroll
      for (int r = 0; r < 4; ++r)
        #pragma unroll
        for (int cc = 0; cc < 4; ++cc) {
          accq[r][cc] = fmaf(a[r], b[cc], accq[r][cc]);
          acck[r][cc] = fmaf(a[r], c[cc], acck[r][cc]);
        }
    }
  }
  float4 bq4 = *(const float4*)(bqv + i0 + tx*4);
  float4 bk4 = *(const float4*)(bkv + i0 + tx*4);
  #pragma unroll
  for (int r = 0; r < 4; ++r) {
    int trow = t0 + ty*4 + r;
    float4 oq = { accq[r][0]+bq4.x, accq[r][1]+bq4.y, accq[r][2]+bq4.z, accq[r][3]+bq4.w };
    float4 ok = { acck[r][0]+bk4.x, acck[r][1]+bk4.y, acck[r][2]+bk4.z, acck[r][3]+bk4.w };
    *(float4*)(qout + (size_t)trow * D + i0 + tx*4) = oq;
    *(float4*)(kout + (size_t)trow * D + i0 + tx*4) = ok;
  }
}

__global__ __launch_bounds__(256) void colsum_kernel(const float* __restrict__ x,
                                                     float* __restrict__ xsum)
{
  int d = blockIdx.x * 256 + threadIdx.x;
  int tbase = blockIdx.y * 256;
  float s = 0.f;
  for (int t = 0; t < 256; ++t) s += x[(size_t)(tbase + t) * D + d];
  atomicAdd(&xsum[d], s);
}

__global__ __launch_bounds__(256) void attn_kernel(
    const float* __restrict__ x, const float* __restrict__ q,
    const float* __restrict__ kmat, const float* __restrict__ xsum,
    float* __restrict__ out)
{
  __shared__ __align__(16) float scl[TQ][UMAX];
  __shared__ float e0s[TQ], dinv[TQ];
  const int tid = threadIdx.x, lane = tid & 63, wv = tid >> 6;
  const int t0 = blockIdx.x * TQ;
  const int lo_u = max(0, t0 - WINDOW);
  const int hi_u = min(S, t0 + TQ - 1 + WINDOW);
  const int ucnt = hi_u - lo_u;
  for (int i = tid; i < TQ * UMAX; i += 256) (&scl[0][0])[i] = 0.f;
  __syncthreads();
  {
    const int tiB = wv * 4;
    float4 qf[4][4];
    #pragma unroll
    for (int g = 0; g < 4; ++g) {
      int t = t0 + tiB + g;
      #pragma unroll
      for (int j = 0; j < 4; ++j)
        qf[g][j] = *(const float4*)(q + (size_t)t * D + lane*4 + j*256);
    }
    const int wlo = max(0, t0 + tiB - WINDOW);
    const int whi = min(S, t0 + tiB + 3 + WINDOW);
    for (int s = wlo; s < whi; ++s) {
      float4 kf[4];
      #pragma unroll
      for (int j = 0; j < 4; ++j)
        kf[j] = *(const float4*)(kmat + (size_t)s * D + lane*4 + j*256);
      float acc[4];
      #pragma unroll
      for (int g = 0; g < 4; ++g) {
        float v = 0.f;
        #pragma unroll
        for (int j = 0; j < 4; ++j) {
          v = fmaf(qf[g][j].x, kf[j].x, v);
          v = fmaf(qf[g][j].y, kf[j].y, v);
          v = fmaf(qf[g][j].z, kf[j].z, v);
          v = fmaf(qf[g][j].w, kf[j].w, v);
        }
        acc[g] = v;
      }
      #pragma unroll
      for (int g = 0; g < 4; ++g) {
        float tot = wave_sum(acc[g]);
        int t = t0 + tiB + g;
        if (lane == 0 && s >= t - WINDOW && s < t + WINDOW)
          scl[tiB + g][s - lo_u] = tot;
      }
    }
  }
  __syncthreads();
  #pragma unroll
  for (int g = 0; g < 4; ++g) {
    int ti = wv * 4 + g;
    int t = t0 + ti;
    int lo = max(0, t - WINDOW), hi = min(S, t + WINDOW);
    int cnt = hi - lo, off = lo - lo_u;
    float m = 0.f;
    for (int i = lane; i < cnt; i += 64) m = fmaxf(m, scl[ti][off + i]);
    m = wave_max(m);
    float e0 = __expf(-m);
    float ssum = 0.f;
    for (int i = lane; i < cnt; i += 64) {
      float e = __expf(scl[ti][off + i] - m);
      ssum += e;
      scl[ti][off + i] = e - e0;
    }
    ssum = wave_sum(ssum);
    if (lane == 0) {
      dinv[ti] = 1.f / (ssum + (float)(S - cnt) * e0);
      e0s[ti] = e0;
    }
  }
  __syncthreads();
  {
    const int c4 = tid * 4;
    float4 acc[TQ];
    #pragma unroll
    for (int ti = 0; ti < TQ; ++ti) acc[ti] = make_float4(0.f, 0.f, 0.f, 0.f);
    for (int su = 0; su < ucnt; su += 4) {
      float4 xr[4];
      #pragma unroll
      for (int u = 0; u < 4; ++u)
        xr[u] = *(const float4*)(x + (size_t)(lo_u + su + u) * D + c4);
      #pragma unroll
      for (int ti = 0; ti < TQ; ++ti) {
        float4 w4 = *(const float4*)&scl[ti][su];
        float wvv[4] = {w4.x, w4.y, w4.z, w4.w};
        #pragma unroll
        for (int u = 0; u < 4; ++u) {
          acc[ti].x = fmaf(wvv[u], xr[u].x, acc[ti].x);
          acc[ti].y = fmaf(wvv[u], xr[u].y, acc[ti].y);
          acc[ti].z = fmaf(wvv[u], xr[u].z, acc[ti].z);
          acc[ti].w = fmaf(wvv[u], xr[u].w, acc[ti].w);
        }
      }
    }
    float4 xsv = *(const float4*)(xsum + c4);
    #pragma unroll
    for (int ti = 0; ti < TQ; ++ti) {
      float e0 = e0s[ti], di = dinv[ti];
      float4 o;
      o.x = (acc[ti].x + e0 * xsv.x) * di;
      o.y = (acc[ti].y + e0 * xsv.y) * di;
      o.z = (acc[ti].z + e0 * xsv.z) * di;
      o.w = (acc[ti].w + e0 * xsv.w) * di;
      *(float4*)(out + (size_t)(t0 + ti) * D + c4) = o;
    }
  }
}

extern "C" void kernel_launch(void* const* d_in, const int* in_sizes, int n_in,
                              void* d_out, int out_size, void* d_ws, size_t ws_size,
                              hipStream_t stream) {
  const float* x  = (const float*)d_in[0];
  const float* Wq = (const float*)d_in[1];
  const float* bq = (const float*)d_in[2];
  const float* Wk = (const float*)d_in[3];
  const float* bk = (const float*)d_in[4];
  float* outp = (float*)d_out;

  const size_t SD = (size_t)S * D;
  const size_t DD = (size_t)D * D;

  // fp32 scalar region: [xsum D][a S][b S] (zeroed in wuv) [uu 2D][vv 2D][cbuf 16]
  float* xsum = (float*)d_ws;            // D
  float* a    = xsum + D;                // S
  float* b    = a + S;                   // S
  float* uu   = b + S;                   // 2D (two n-slices)
  float* vv   = uu + 2 * D;              // 2D
  float* cbuf = vv + 2 * D;              // 16

  u16t* xhi  = (u16t*)(cbuf + 16);
  u16t* xlo  = xhi + SD;
  u16t* xT   = xlo + SD;
  u16t* wqth = xT + SD;
  u16t* wqtl = wqth + DD;
  u16t* wkth = wqtl + DD;
  u16t* wktl = wkth + DD;
  u16t* mh   = wktl + DD;
  u16t* ml   = mh + DD;
  u16t* yh   = ml + DD;
  u16t* yl   = yh + SD;
  float* band = (float*)(yl + SD);                // S*BAND f32
  u16t*  Pb   = (u16t*)(band + (size_t)S * BAND); // S*BAND u16
  float* e0d  = (float*)(Pb + (size_t)S * BAND);  // S f32
  size_t needed = (size_t)((char*)(e0d + S) - (char*)d_ws);

  if (ws_size >= needed) {
    wuv_kernel<<<dim3(16, 16, 3), 256, 0, stream>>>(
        Wq, Wk, bq, bk, uu, vv, cbuf, wqth, wqtl, wkth, wktl, xsum);
    prep_kernel<<<dim3(S / 64, D / 64), 256, 0, stream>>>(x, uu, vv, xhi, xlo, xT, xsum, a, b);
    m_kernel<<<dim3(D / 64, D / 64), 256, 0, stream>>>(wqth, wqtl, wkth, wktl, mh, ml);
    y_kernel<<<dim3(S / 128, D / 128), 256, 0, stream>>>(xhi, xlo, mh, ml, yh, yl);
    scores_kernel<<<dim3(S / 64, 5), 256, 0, stream>>>(xhi, xlo, yh, yl, a, b, cbuf, band);
    softmax_kernel<<<S / 4, 256, 0, stream>>>(band, Pb, e0d);
    pv_kernel<<<dim3(S / 64, D / 128), 256, 0, stream>>>(Pb, xT, e0d, xsum, outp);
  } else {
    float* xs2  = (float*)d_ws;
    float* q    = xs2 + D;
    float* kbuf = q + SD;
    (void)hipMemsetAsync(xs2, 0, D * sizeof(float), stream);
    colsum_kernel<<<dim3(D / 256, S / 256), 256, 0, stream>>>(x, xs2);
    proj_kernel<<<dim3(S / 64, D / 64), 256, 0, stream>>>(x, Wq, bq, Wk, bk, q, kbuf);
    attn_kernel<<<S / TQ, 256, 0, stream>>>(x, q, kbuf, xs2, outp);
  }
}

// Round 8
// 278.754 us; speedup vs baseline: 2.2997x; 1.0333x over previous
//
#include <hip/hip_runtime.h>

#define S 8192
#define D 1024
#define WINDOW 128
#define TQ 16
#define UMAX 288
#define BK 32
#define PAD 68
#define BAND 320   // band width: s in [t_tile64-128, t_tile64+192)

typedef __attribute__((ext_vector_type(8))) short short8;
typedef __attribute__((ext_vector_type(4))) float floatx4;
typedef __attribute__((ext_vector_type(4))) unsigned short ushort4v;
typedef unsigned short u16t;

__device__ __forceinline__ float wave_sum(float v) {
  #pragma unroll
  for (int off = 32; off > 0; off >>= 1) v += __shfl_xor(v, off, 64);
  return v;
}
__device__ __forceinline__ float wave_max(float v) {
  #pragma unroll
  for (int off = 32; off > 0; off >>= 1) v = fmaxf(v, __shfl_xor(v, off, 64));
  return v;
}
__device__ __forceinline__ unsigned int f2bf_rn(float f) {
  unsigned int u = __float_as_uint(f);
  return (u + 0x7fffu + ((u >> 16) & 1u)) >> 16;
}

#define GLDS(gp, lp) __builtin_amdgcn_global_load_lds( \
    (const __attribute__((address_space(1))) void*)(gp), \
    (__attribute__((address_space(3))) void*)(lp), 16, 0, 0)

// LDS bank-conflict-free addressing for [row][32 u16] buffers staged via
// global_load_lds (linear dest).  Source col-chunk is pre-swizzled so the
// 16x16 frag read (16-lane, 64B row stride) lands on distinct bank groups.
//   staging: thread loads global chunk ((lane&3) ^ ((lane>>3)&3))
//   read:    wanted chunk q=(lane>>4) lives at slot q ^ ((lane>>1)&3)
// (verified round 1: SQ_LDS_BANK_CONFLICT 4.19M -> 0)
//
// NOTE (round 7 lesson): do NOT XCD-swizzle y's grid. Default dispatch order
// keeps all XCDs in the same B-panel window -> A is HBM-read once (FETCH
// ~35MB); per-XCD panel assignment makes 8 concurrent 32MB A-streams that
// thrash the 256MB L3 (FETCH 147MB, +10us).

// ---------------------------------------------------------------------------
// Merged W-prep dispatch (no memset node):
//  z=0: transpose Wq -> wqth/wqtl     z=1: transpose Wk -> wkth/wktl
//  z=2, by==0, bx<8 : uv direct (2 n-slices, no atomics)
//  z=2, by==0, bx==8: cbuf = bq.bk
//  z=2, by>=1       : zero xsum/a/b region (consumed only by NEXT dispatch)
// ---------------------------------------------------------------------------
__global__ __launch_bounds__(256) void wuv_kernel(
    const float* __restrict__ Wq, const float* __restrict__ Wk,
    const float* __restrict__ bq, const float* __restrict__ bk,
    float* __restrict__ uu, float* __restrict__ vv, float* __restrict__ cbuf,
    u16t* __restrict__ wqth, u16t* __restrict__ wqtl,
    u16t* __restrict__ wkth, u16t* __restrict__ wktl,
    float* __restrict__ zreg)
{
  __shared__ float tile[64][65];
  __shared__ float cr[4];
  const int t = threadIdx.x;
  if (blockIdx.z == 2) {
    if (blockIdx.y == 0) {
      if (blockIdx.x < 8) {          // uv: direct stores to slice nh
        const int i  = (blockIdx.x & 3) * 256 + t;
        const int nh = blockIdx.x >> 2;
        float us = 0.f, vs = 0.f;
        for (int n = nh * 512; n < nh * 512 + 512; ++n) {
          us += Wq[(size_t)n * D + i] * bk[n];
          vs += Wk[(size_t)n * D + i] * bq[n];
        }
        uu[(size_t)nh * D + i] = us;
        vv[(size_t)nh * D + i] = vs;
      } else if (blockIdx.x == 8) {  // cbuf
        float cs = 0.f;
        for (int n = t; n < D; n += 256) cs += bq[n] * bk[n];
        cs = wave_sum(cs);
        if ((t & 63) == 0) cr[t >> 6] = cs;
        __syncthreads();
        if (t == 0) cbuf[0] = cr[0] + cr[1] + cr[2] + cr[3];
      }
    } else {                         // zero xsum/a/b (D + 2S floats)
      int fb  = (blockIdx.y - 1) * 16 + blockIdx.x;  // 0..239
      int idx = fb * 256 + t;
      if (idx < D + 2 * S) zreg[idx] = 0.f;
    }
    return;
  }
  const float* W = blockIdx.z ? Wk : Wq;
  u16t* oh = blockIdx.z ? wkth : wqth;
  u16t* ol = blockIdx.z ? wktl : wqtl;
  const int n0 = blockIdx.x * 64;   // source row
  const int i0 = blockIdx.y * 64;   // source col
  #pragma unroll
  for (int p = 0; p < 4; ++p) {
    int r = (t >> 4) + p * 16;
    int c = (t & 15) * 4;
    float4 vf = *(const float4*)(W + (size_t)(n0 + r) * D + i0 + c);
    tile[r][c+0] = vf.x; tile[r][c+1] = vf.y; tile[r][c+2] = vf.z; tile[r][c+3] = vf.w;
  }
  __syncthreads();
  #pragma unroll
  for (int p = 0; p < 4; ++p) {
    int ii = (t >> 4) + p * 16;
    int nn = (t & 15) * 4;
    ushort4v h, l;
    #pragma unroll
    for (int e = 0; e < 4; ++e) {
      float f = tile[nn + e][ii];
      unsigned int hb = f2bf_rn(f);
      float hf = __uint_as_float(hb << 16);
      h[e] = (u16t)hb;
      l[e] = (u16t)f2bf_rn(f - hf);
    }
    size_t idx = (size_t)(i0 + ii) * D + n0 + nn;
    *(ushort4v*)(oh + idx) = h;
    *(ushort4v*)(ol + idx) = l;
  }
}

// ---------------------------------------------------------------------------
// prep: read x tile once -> xhi/xlo (split), xT (bf16 transpose),
//       xsum partials, a = x.u partials, b = x.v partials  (u = uu0+uu1)
// ---------------------------------------------------------------------------
__global__ __launch_bounds__(256) void prep_kernel(
    const float* __restrict__ x, const float* __restrict__ uu,
    const float* __restrict__ vv, u16t* __restrict__ xhi, u16t* __restrict__ xlo,
    u16t* __restrict__ xT, float* __restrict__ xsum,
    float* __restrict__ a, float* __restrict__ b)
{
  __shared__ float tile[64][65];
  const int s0 = blockIdx.x * 64;
  const int d0 = blockIdx.y * 64;
  const int t = threadIdx.x;
  #pragma unroll
  for (int p = 0; p < 4; ++p) {
    int r = (t >> 4) + p * 16;
    int c = (t & 15) * 4;
    float4 vf = *(const float4*)(x + (size_t)(s0 + r) * D + d0 + c);
    float f[4] = {vf.x, vf.y, vf.z, vf.w};
    tile[r][c+0] = vf.x; tile[r][c+1] = vf.y; tile[r][c+2] = vf.z; tile[r][c+3] = vf.w;
    ushort4v h, l;
    #pragma unroll
    for (int e = 0; e < 4; ++e) {
      unsigned int hb = f2bf_rn(f[e]);
      float hf = __uint_as_float(hb << 16);
      h[e] = (u16t)hb;
      l[e] = (u16t)f2bf_rn(f[e] - hf);
    }
    size_t idx = (size_t)(s0 + r) * D + d0 + c;
    *(ushort4v*)(xhi + idx) = h;
    *(ushort4v*)(xlo + idx) = l;
  }
  __syncthreads();
  // transpose write
  #pragma unroll
  for (int p = 0; p < 4; ++p) {
    int dd = (t >> 4) + p * 16;
    int ss = (t & 15) * 4;
    ushort4v o;
    #pragma unroll
    for (int e = 0; e < 4; ++e) o[e] = (u16t)f2bf_rn(tile[ss + e][dd]);
    *(ushort4v*)(xT + (size_t)(d0 + dd) * S + s0 + ss) = o;
  }
  // reductions
  if (t < 64) {               // column sums -> xsum[d0+t]
    float s = 0.f;
    #pragma unroll 8
    for (int r = 0; r < 64; ++r) s += tile[r][t];
    atomicAdd(&xsum[d0 + t], s);
  } else if (t < 128) {       // a rows
    int r = t - 64;
    float s = 0.f;
    for (int c = 0; c < 64; ++c) s += tile[r][c] * (uu[d0 + c] + uu[D + d0 + c]);
    atomicAdd(&a[s0 + r], s);
  } else if (t < 192) {       // b rows
    int r = t - 128;
    float s = 0.f;
    for (int c = 0; c < 64; ++c) s += tile[r][c] * (vv[d0 + c] + vv[D + d0 + c]);
    atomicAdd(&b[s0 + r], s);
  }
}

// ---------------------------------------------------------------------------
// M[i][j] = sum_n Wq[n][i]Wk[n][j]; hi/lo 3-term.  16x16x32, swizzled LDS.
// ---------------------------------------------------------------------------
__global__ __launch_bounds__(256) void m_kernel(
    const u16t* __restrict__ wqth, const u16t* __restrict__ wqtl,
    const u16t* __restrict__ wkth, const u16t* __restrict__ wktl,
    u16t* __restrict__ mh, u16t* __restrict__ ml)
{
  __shared__ __align__(16) u16t Mbuf[4][64 * BK];  // 0:Ah 1:Al 2:Bh 3:Bl

  const int tid  = threadIdx.x;
  const int lane = tid & 63;
  const int wv   = tid >> 6;
  const int i0   = blockIdx.x * 64;
  const int j0   = blockIdx.y * 64;

  floatx4 acc[2][2] = {};
  const int m0w = (wv & 1) * 32;
  const int n0w = (wv >> 1) * 32;
  const int srow = lane >> 2;
  const int scolw = ((lane & 3) ^ ((lane >> 3) & 3)) * 8;
  const int rs    = (((lane >> 4) ^ ((lane >> 1) & 3)) * 8);

  for (int k0 = 0; k0 < D; k0 += BK) {
    __syncthreads();
    {
      const u16t* src = (wv == 0) ? wqth : (wv == 1) ? wqtl : (wv == 2) ? wkth : wktl;
      const int base  = (wv < 2) ? i0 : j0;
      #pragma unroll
      for (int sg = 0; sg < 4; ++sg) {
        int row = base + sg * 16 + srow;
        size_t g = (size_t)row * D + k0 + scolw;
        GLDS(src + g, &Mbuf[wv][sg * 512]);
      }
    }
    __syncthreads();
    short8 ah[2], al[2], bh[2], bl[2];
    #pragma unroll
    for (int t = 0; t < 2; ++t) {
      int ar = (m0w + t * 16 + (lane & 15)) * BK + rs;
      int br = (n0w + t * 16 + (lane & 15)) * BK + rs;
      ah[t] = *(const short8*)&Mbuf[0][ar];
      al[t] = *(const short8*)&Mbuf[1][ar];
      bh[t] = *(const short8*)&Mbuf[2][br];
      bl[t] = *(const short8*)&Mbuf[3][br];
    }
    #pragma unroll
    for (int mt = 0; mt < 2; ++mt)
      #pragma unroll
      for (int nt = 0; nt < 2; ++nt) {
        acc[mt][nt] = __builtin_amdgcn_mfma_f32_16x16x32_bf16(ah[mt], bh[nt], acc[mt][nt], 0, 0, 0);
        acc[mt][nt] = __builtin_amdgcn_mfma_f32_16x16x32_bf16(ah[mt], bl[nt], acc[mt][nt], 0, 0, 0);
        acc[mt][nt] = __builtin_amdgcn_mfma_f32_16x16x32_bf16(al[mt], bh[nt], acc[mt][nt], 0, 0, 0);
      }
  }
  #pragma unroll
  for (int mt = 0; mt < 2; ++mt)
    #pragma unroll
    for (int nt = 0; nt < 2; ++nt) {
      int j = j0 + n0w + nt * 16 + (lane & 15);
      int i = i0 + m0w + mt * 16 + (lane >> 4) * 4;
      #pragma unroll
      for (int r = 0; r < 4; ++r) {
        float f = acc[mt][nt][r];
        unsigned int hb = f2bf_rn(f);
        float hf = __uint_as_float(hb << 16);
        size_t idx = (size_t)(i + r) * D + j;
        mh[idx] = (u16t)hb;
        ml[idx] = (u16t)f2bf_rn(f - hf);
      }
    }
}

// ---------------------------------------------------------------------------
// Y[s][i] = sum_j x[s][j]*M[i][j]; hi/lo 3-term. BK=64 two-half staging,
// swizzled LDS, 16x16x32. 128x128 tile, 256 thr, 64KB LDS -> 2 blocks/CU.
// (verified: 53.6us, MfmaUtil ~40%, conflicts 0, FETCH ~35MB; default
// block order — no XCD swizzle, see note above)
// ---------------------------------------------------------------------------
__global__ __launch_bounds__(256) void y_kernel(
    const u16t* __restrict__ xhi, const u16t* __restrict__ xlo,
    const u16t* __restrict__ mhp, const u16t* __restrict__ mlp,
    u16t* __restrict__ yh, u16t* __restrict__ yl)
{
  __shared__ __align__(16) u16t Ah[2 * 128 * BK];
  __shared__ __align__(16) u16t Al[2 * 128 * BK];
  __shared__ __align__(16) u16t Bh[2 * 128 * BK];
  __shared__ __align__(16) u16t Bl[2 * 128 * BK];

  const int tid  = threadIdx.x;
  const int lane = tid & 63;
  const int wv   = tid >> 6;
  const int s0   = blockIdx.x * 128;
  const int i0   = blockIdx.y * 128;

  floatx4 acc[4][4] = {};
  const int m0w  = (wv & 1) * 64;
  const int n0w  = (wv >> 1) * 64;
  const int srow = lane >> 2;
  const int scolw = ((lane & 3) ^ ((lane >> 3) & 3)) * 8;
  const int rs    = (((lane >> 4) ^ ((lane >> 1) & 3)) * 8);

  for (int k0 = 0; k0 < D; k0 += 64) {
    __syncthreads();
    #pragma unroll
    for (int h = 0; h < 2; ++h) {
      #pragma unroll
      for (int sg = 0; sg < 2; ++sg) {
        int seg  = wv * 2 + sg;
        int arow = s0 + seg * 16 + srow;
        int brow = i0 + seg * 16 + srow;
        size_t ga = (size_t)arow * D + k0 + h * 32 + scolw;
        size_t gb = (size_t)brow * D + k0 + h * 32 + scolw;
        int lb = h * 4096 + seg * 512;
        GLDS(xhi + ga, &Ah[lb]);
        GLDS(xlo + ga, &Al[lb]);
        GLDS(mhp + gb, &Bh[lb]);
        GLDS(mlp + gb, &Bl[lb]);
      }
    }
    __syncthreads();
    #pragma unroll
    for (int h = 0; h < 2; ++h) {
      short8 ah[4], al[4], bh[4], bl[4];
      #pragma unroll
      for (int t = 0; t < 4; ++t) {
        int ar = h * 4096 + (m0w + t * 16 + (lane & 15)) * BK + rs;
        int br = h * 4096 + (n0w + t * 16 + (lane & 15)) * BK + rs;
        ah[t] = *(const short8*)&Ah[ar];
        al[t] = *(const short8*)&Al[ar];
        bh[t] = *(const short8*)&Bh[br];
        bl[t] = *(const short8*)&Bl[br];
      }
      #pragma unroll
      for (int mt = 0; mt < 4; ++mt)
        #pragma unroll
        for (int nt = 0; nt < 4; ++nt) {
          acc[mt][nt] = __builtin_amdgcn_mfma_f32_16x16x32_bf16(ah[mt], bh[nt], acc[mt][nt], 0, 0, 0);
          acc[mt][nt] = __builtin_amdgcn_mfma_f32_16x16x32_bf16(ah[mt], bl[nt], acc[mt][nt], 0, 0, 0);
          acc[mt][nt] = __builtin_amdgcn_mfma_f32_16x16x32_bf16(al[mt], bh[nt], acc[mt][nt], 0, 0, 0);
        }
    }
  }
  #pragma unroll
  for (int mt = 0; mt < 4; ++mt)
    #pragma unroll
    for (int nt = 0; nt < 4; ++nt) {
      int i = i0 + n0w + nt * 16 + (lane & 15);
      int s = s0 + m0w + mt * 16 + (lane >> 4) * 4;
      #pragma unroll
      for (int r = 0; r < 4; ++r) {
        float f = acc[mt][nt][r];
        unsigned int hb = f2bf_rn(f);
        float hf = __uint_as_float(hb << 16);
        size_t idx = (size_t)(s + r) * D + i;
        yh[idx] = (u16t)hb;
        yl[idx] = (u16t)f2bf_rn(f - hf);
      }
    }
}

// ---------------------------------------------------------------------------
// Banded scores, 64x64 tiles: band[t][j] = x_t.Y_s + a[t] + b[s] + c
// (s = (t&~63) - 128 + j, j in [0,320)), hi/lo 3-term, swizzled LDS.
// ---------------------------------------------------------------------------
__global__ __launch_bounds__(256) void scores_kernel(
    const u16t* __restrict__ xhi, const u16t* __restrict__ xlo,
    const u16t* __restrict__ yh, const u16t* __restrict__ yl,
    const float* __restrict__ a, const float* __restrict__ b,
    const float* __restrict__ cbuf, float* __restrict__ band)
{
  __shared__ __align__(16) u16t Ah[2 * 64 * BK];
  __shared__ __align__(16) u16t Al[2 * 64 * BK];
  __shared__ __align__(16) u16t Bh[2 * 64 * BK];
  __shared__ __align__(16) u16t Bl[2 * 64 * BK];

  const int tid  = threadIdx.x;
  const int lane = tid & 63;
  const int wv   = tid >> 6;
  const int t0   = blockIdx.x * 64;
  const int jt   = blockIdx.y;              // 0..4
  const int s_base = t0 - 128 + jt * 64;
  const float cval = cbuf[0];

  floatx4 acc[2][2] = {};
  const int m0w  = (wv & 1) * 32;
  const int n0w  = (wv >> 1) * 32;
  const int srow = lane >> 2;
  const int scolw = ((lane & 3) ^ ((lane >> 3) & 3)) * 8;
  const int rs    = (((lane >> 4) ^ ((lane >> 1) & 3)) * 8);

  for (int k0 = 0; k0 < D; k0 += 64) {
    __syncthreads();
    #pragma unroll
    for (int h = 0; h < 2; ++h) {
      int arow = t0 + wv * 16 + srow;
      int brow = s_base + wv * 16 + srow;
      brow = min(max(brow, 0), S - 1);
      size_t ga = (size_t)arow * D + k0 + h * 32 + scolw;
      size_t gb = (size_t)brow * D + k0 + h * 32 + scolw;
      int lb = h * 2048 + wv * 512;
      GLDS(xhi + ga, &Ah[lb]);
      GLDS(xlo + ga, &Al[lb]);
      GLDS(yh + gb, &Bh[lb]);
      GLDS(yl + gb, &Bl[lb]);
    }
    __syncthreads();
    #pragma unroll
    for (int h = 0; h < 2; ++h) {
      short8 ah[2], al[2], bh[2], bl[2];
      #pragma unroll
      for (int t = 0; t < 2; ++t) {
        int ar = h * 2048 + (m0w + t * 16 + (lane & 15)) * BK + rs;
        int br = h * 2048 + (n0w + t * 16 + (lane & 15)) * BK + rs;
        ah[t] = *(const short8*)&Ah[ar];
        al[t] = *(const short8*)&Al[ar];
        bh[t] = *(const short8*)&Bh[br];
        bl[t] = *(const short8*)&Bl[br];
      }
      #pragma unroll
      for (int mt = 0; mt < 2; ++mt)
        #pragma unroll
        for (int nt = 0; nt < 2; ++nt) {
          acc[mt][nt] = __builtin_amdgcn_mfma_f32_16x16x32_bf16(ah[mt], bh[nt], acc[mt][nt], 0, 0, 0);
          acc[mt][nt] = __builtin_amdgcn_mfma_f32_16x16x32_bf16(ah[mt], bl[nt], acc[mt][nt], 0, 0, 0);
          acc[mt][nt] = __builtin_amdgcn_mfma_f32_16x16x32_bf16(al[mt], bh[nt], acc[mt][nt], 0, 0, 0);
        }
    }
  }
  #pragma unroll
  for (int mt = 0; mt < 2; ++mt)
    #pragma unroll
    for (int nt = 0; nt < 2; ++nt) {
      int n_loc = n0w + nt * 16 + (lane & 15);
      int s = s_base + n_loc;
      float bv = (s >= 0 && s < S) ? b[s] : 0.f;
      #pragma unroll
      for (int r = 0; r < 4; ++r) {
        int m_loc = m0w + mt * 16 + (lane >> 4) * 4 + r;
        int t = t0 + m_loc;
        bool inwin = (s >= t - WINDOW) && (s < t + WINDOW) && (s >= 0) && (s < S);
        float sv = inwin ? (acc[mt][nt][r] + a[t] + bv + cval) : 0.f;
        band[(size_t)t * BAND + jt * 64 + n_loc] = sv;
      }
    }
}

// ---------------------------------------------------------------------------
// Softmax over band (320); P = (e - e0)*dinv as bf16; e0d = e0*dinv.
// ---------------------------------------------------------------------------
__global__ __launch_bounds__(256) void softmax_kernel(
    const float* __restrict__ band, u16t* __restrict__ Pb, float* __restrict__ e0d)
{
  const int lane = threadIdx.x & 63;
  const int w    = threadIdx.x >> 6;
  const int t    = blockIdx.x * 4 + w;
  const float* row = band + (size_t)t * BAND;
  float v[5];
  float mx = 0.f;
  #pragma unroll
  for (int i = 0; i < 5; ++i) {
    v[i] = row[i * 64 + lane];
    mx = fmaxf(mx, v[i]);
  }
  mx = wave_max(mx);
  float e0 = __expf(-mx);
  float ss = 0.f;
  #pragma unroll
  for (int i = 0; i < 5; ++i) {
    v[i] = __expf(v[i] - mx);
    ss += v[i];
  }
  ss = wave_sum(ss);
  float dinv = 1.f / (ss + (float)(S - BAND) * e0);
  #pragma unroll
  for (int i = 0; i < 5; ++i)
    Pb[(size_t)t * BAND + i * 64 + lane] = (u16t)f2bf_rn((v[i] - e0) * dinv);
  if (lane == 0) e0d[t] = e0 * dinv;
}

// ---------------------------------------------------------------------------
// PV: out[t][d] = sum_j Pb[t][j]*x[origin+j][d] + e0d[t]*xsum[d].
// 64-row t-tiles, K=320, swizzled LDS, 16x16x32.
// ---------------------------------------------------------------------------
__global__ __launch_bounds__(256) void pv_kernel(
    const u16t* __restrict__ Pb, const u16t* __restrict__ xT,
    const float* __restrict__ e0d, const float* __restrict__ xsum,
    float* __restrict__ out)
{
  __shared__ __align__(16) u16t Ab[2 * 64 * BK];
  __shared__ __align__(16) u16t Bb[2 * 128 * BK];

  const int tid  = threadIdx.x;
  const int lane = tid & 63;
  const int wv   = tid >> 6;
  const int t0   = blockIdx.x * 64;
  const int d0   = blockIdx.y * 128;
  const int origin = t0 - 128;

  floatx4 acc[2][4] = {};
  const int m0w  = (wv & 1) * 32;   // t rows within tile
  const int n0w  = (wv >> 1) * 64;  // d cols within tile
  const int srow = lane >> 2;
  const int scolw = ((lane & 3) ^ ((lane >> 3) & 3)) * 8;
  const int rs    = (((lane >> 4) ^ ((lane >> 1) & 3)) * 8);

  for (int k0 = 0; k0 < BAND; k0 += 64) {
    __syncthreads();
    #pragma unroll
    for (int h = 0; h < 2; ++h) {
      {
        int arow = t0 + wv * 16 + srow;
        size_t ga = (size_t)arow * BAND + k0 + h * 32 + scolw;
        int lb = h * 2048 + wv * 512;
        GLDS(Pb + ga, &Ab[lb]);
      }
      #pragma unroll
      for (int sg = 0; sg < 2; ++sg) {
        int seg  = wv * 2 + sg;
        int brow = d0 + seg * 16 + srow;
        int s_g  = origin + k0 + h * 32 + scolw;
        s_g = min(max(s_g, 0), S - 8);
        size_t gb = (size_t)brow * S + s_g;
        int lb = h * 4096 + seg * 512;
        GLDS(xT + gb, &Bb[lb]);
      }
    }
    __syncthreads();
    #pragma unroll
    for (int h = 0; h < 2; ++h) {
      short8 af[2], bf[4];
      #pragma unroll
      for (int t = 0; t < 2; ++t) {
        int ar = h * 2048 + (m0w + t * 16 + (lane & 15)) * BK + rs;
        af[t] = *(const short8*)&Ab[ar];
      }
      #pragma unroll
      for (int t = 0; t < 4; ++t) {
        int br = h * 4096 + (n0w + t * 16 + (lane & 15)) * BK + rs;
        bf[t] = *(const short8*)&Bb[br];
      }
      #pragma unroll
      for (int mt = 0; mt < 2; ++mt)
        #pragma unroll
        for (int nt = 0; nt < 4; ++nt)
          acc[mt][nt] = __builtin_amdgcn_mfma_f32_16x16x32_bf16(af[mt], bf[nt], acc[mt][nt], 0, 0, 0);
    }
  }
  #pragma unroll
  for (int mt = 0; mt < 2; ++mt)
    #pragma unroll
    for (int nt = 0; nt < 4; ++nt) {
      int n_g = d0 + n0w + nt * 16 + (lane & 15);
      float xs = xsum[n_g];
      #pragma unroll
      for (int r = 0; r < 4; ++r) {
        int m_g = t0 + m0w + mt * 16 + (lane >> 4) * 4 + r;
        out[(size_t)m_g * D + n_g] = acc[mt][nt][r] + e0d[m_g] * xs;
      }
    }
}

// ---------------------------------------------------------------------------
// Fallback path (small workspace): fp32 proj + VALU attn
// ---------------------------------------------------------------------------
__global__ __launch_bounds__(256) void proj_kernel(
    const float* __restrict__ x, const float* __restrict__ Wq,
    const float* __restrict__ bqv, const float* __restrict__ Wk,
    const float* __restrict__ bkv, float* __restrict__ qout,
    float* __restrict__ kout)
{
  __shared__ __align__(16) float xs[BK][PAD];
  __shared__ __align__(16) float wqs[BK][PAD];
  __shared__ __align__(16) float wks[BK][PAD];
  const int tid = threadIdx.x;
  const int tx = tid & 15, ty = tid >> 4;
  const int t0 = blockIdx.x * 64, i0 = blockIdx.y * 64;
  float accq[4][4] = {}, acck[4][4] = {};
  const int lrow0 = tid >> 3, lc4 = (tid & 7) * 4;
  for (int k0 = 0; k0 < D; k0 += BK) {
    __syncthreads();
    #pragma unroll
    for (int p = 0; p < 2; ++p) {
      int row = lrow0 + p * 32;
      float4 a = *(const float4*)(x  + (size_t)(t0 + row) * D + k0 + lc4);
      float4 b = *(const float4*)(Wq + (size_t)(i0 + row) * D + k0 + lc4);
      float4 c = *(const float4*)(Wk + (size_t)(i0 + row) * D + k0 + lc4);
      xs [lc4+0][row]=a.x; xs [lc4+1][row]=a.y; xs [lc4+2][row]=a.z; xs [lc4+3][row]=a.w;
      wqs[lc4+0][row]=b.x; wqs[lc4+1][row]=b.y; wqs[lc4+2][row]=b.z; wqs[lc4+3][row]=b.w;
      wks[lc4+0][row]=c.x; wks[lc4+1][row]=c.y; wks[lc4+2][row]=c.z; wks[lc4+3][row]=c.w;
    }
    __syncthreads();
    #pragma unroll
    for (int kk = 0; kk < BK; ++kk) {
      float4 av = *(const float4*)&xs [kk][ty*4];
      float4 bv = *(const float4*)&wqs[kk][tx*4];
      float4 cv = *(const float4*)&wks[kk][tx*4];
      float a[4] = {av.x, av.y, av.z, av.w};
      float b[4] = {bv.x, bv.y, bv.z, bv.w};
      float c[4] = {cv.x, cv.y, cv.z, cv.w};
      #pragma unroll
      for (int r = 0; r < 4; ++r)
        #pragma unroll
        for (int cc = 0; cc < 4; ++cc) {
          accq[r][cc] = fmaf(a[r], b[cc], accq[r][cc]);
          acck[r][cc] = fmaf(a[r], c[cc], acck[r][cc]);
        }
    }
  }
  float4 bq4 = *(const float4*)(bqv + i0 + tx*4);
  float4 bk4 = *(const float4*)(bkv + i0 + tx*4);
  #pragma unroll
  for (int r = 0; r < 4; ++r) {
    int trow = t0 + ty*4 + r;
    float4 oq = { accq[r][0]+bq4.x, accq[r][1]+bq4.y, accq[r][2]+bq4.z, accq[r][3]+bq4.w };
    float4 ok = { acck[r][0]+bk4.x, acck[r][1]+bk4.y, acck[r][2]+bk4.z, acck[r][3]+bk4.w };
    *(float4*)(qout + (size_t)trow * D + i0 + tx*4) = oq;
    *(float4*)(kout + (size_t)trow * D + i0 + tx*4) = ok;
  }
}

__global__ __launch_bounds__(256) void colsum_kernel(const float* __restrict__ x,
                                                     float* __restrict__ xsum)
{
  int d = blockIdx.x * 256 + threadIdx.x;
  int tbase = blockIdx.y * 256;
  float s = 0.f;
  for (int t = 0; t < 256; ++t) s += x[(size_t)(tbase + t) * D + d];
  atomicAdd(&xsum[d], s);
}

__global__ __launch_bounds__(256) void attn_kernel(
    const float* __restrict__ x, const float* __restrict__ q,
    const float* __restrict__ kmat, const float* __restrict__ xsum,
    float* __restrict__ out)
{
  __shared__ __align__(16) float scl[TQ][UMAX];
  __shared__ float e0s[TQ], dinv[TQ];
  const int tid = threadIdx.x, lane = tid & 63, wv = tid >> 6;
  const int t0 = blockIdx.x * TQ;
  const int lo_u = max(0, t0 - WINDOW);
  const int hi_u = min(S, t0 + TQ - 1 + WINDOW);
  const int ucnt = hi_u - lo_u;
  for (int i = tid; i < TQ * UMAX; i += 256) (&scl[0][0])[i] = 0.f;
  __syncthreads();
  {
    const int tiB = wv * 4;
    float4 qf[4][4];
    #pragma unroll
    for (int g = 0; g < 4; ++g) {
      int t = t0 + tiB + g;
      #pragma unroll
      for (int j = 0; j < 4; ++j)
        qf[g][j] = *(const float4*)(q + (size_t)t * D + lane*4 + j*256);
    }
    const int wlo = max(0, t0 + tiB - WINDOW);
    const int whi = min(S, t0 + tiB + 3 + WINDOW);
    for (int s = wlo; s < whi; ++s) {
      float4 kf[4];
      #pragma unroll
      for (int j = 0; j < 4; ++j)
        kf[j] = *(const float4*)(kmat + (size_t)s * D + lane*4 + j*256);
      float acc[4];
      #pragma unroll
      for (int g = 0; g < 4; ++g) {
        float v = 0.f;
        #pragma unroll
        for (int j = 0; j < 4; ++j) {
          v = fmaf(qf[g][j].x, kf[j].x, v);
          v = fmaf(qf[g][j].y, kf[j].y, v);
          v = fmaf(qf[g][j].z, kf[j].z, v);
          v = fmaf(qf[g][j].w, kf[j].w, v);
        }
        acc[g] = v;
      }
      #pragma unroll
      for (int g = 0; g < 4; ++g) {
        float tot = wave_sum(acc[g]);
        int t = t0 + tiB + g;
        if (lane == 0 && s >= t - WINDOW && s < t + WINDOW)
          scl[tiB + g][s - lo_u] = tot;
      }
    }
  }
  __syncthreads();
  #pragma unroll
  for (int g = 0; g < 4; ++g) {
    int ti = wv * 4 + g;
    int t = t0 + ti;
    int lo = max(0, t - WINDOW), hi = min(S, t + WINDOW);
    int cnt = hi - lo, off = lo - lo_u;
    float m = 0.f;
    for (int i = lane; i < cnt; i += 64) m = fmaxf(m, scl[ti][off + i]);
    m = wave_max(m);
    float e0 = __expf(-m);
    float ssum = 0.f;
    for (int i = lane; i < cnt; i += 64) {
      float e = __expf(scl[ti][off + i] - m);
      ssum += e;
      scl[ti][off + i] = e - e0;
    }
    ssum = wave_sum(ssum);
    if (lane == 0) {
      dinv[ti] = 1.f / (ssum + (float)(S - cnt) * e0);
      e0s[ti] = e0;
    }
  }
  __syncthreads();
  {
    const int c4 = tid * 4;
    float4 acc[TQ];
    #pragma unroll
    for (int ti = 0; ti < TQ; ++ti) acc[ti] = make_float4(0.f, 0.f, 0.f, 0.f);
    for (int su = 0; su < ucnt; su += 4) {
      float4 xr[4];
      #pragma unroll
      for (int u = 0; u < 4; ++u)
        xr[u] = *(const float4*)(x + (size_t)(lo_u + su + u) * D + c4);
      #pragma unroll
      for (int ti = 0; ti < TQ; ++ti) {
        float4 w4 = *(const float4*)&scl[ti][su];
        float wvv[4] = {w4.x, w4.y, w4.z, w4.w};
        #pragma unroll
        for (int u = 0; u < 4; ++u) {
          acc[ti].x = fmaf(wvv[u], xr[u].x, acc[ti].x);
          acc[ti].y = fmaf(wvv[u], xr[u].y, acc[ti].y);
          acc[ti].z = fmaf(wvv[u], xr[u].z, acc[ti].z);
          acc[ti].w = fmaf(wvv[u], xr[u].w, acc[ti].w);
        }
      }
    }
    float4 xsv = *(const float4*)(xsum + c4);
    #pragma unroll
    for (int ti = 0; ti < TQ; ++ti) {
      float e0 = e0s[ti], di = dinv[ti];
      float4 o;
      o.x = (acc[ti].x + e0 * xsv.x) * di;
      o.y = (acc[ti].y + e0 * xsv.y) * di;
      o.z = (acc[ti].z + e0 * xsv.z) * di;
      o.w = (acc[ti].w + e0 * xsv.w) * di;
      *(float4*)(out + (size_t)(t0 + ti) * D + c4) = o;
    }
  }
}

extern "C" void kernel_launch(void* const* d_in, const int* in_sizes, int n_in,
                              void* d_out, int out_size, void* d_ws, size_t ws_size,
                              hipStream_t stream) {
  const float* x  = (const float*)d_in[0];
  const float* Wq = (const float*)d_in[1];
  const float* bq = (const float*)d_in[2];
  const float* Wk = (const float*)d_in[3];
  const float* bk = (const float*)d_in[4];
  float* outp = (float*)d_out;

  const size_t SD = (size_t)S * D;
  const size_t DD = (size_t)D * D;

  // fp32 scalar region: [xsum D][a S][b S] (zeroed in wuv) [uu 2D][vv 2D][cbuf 16]
  float* xsum = (float*)d_ws;            // D
  float* a    = xsum + D;                // S
  float* b    = a + S;                   // S
  float* uu   = b + S;                   // 2D (two n-slices)
  float* vv   = uu + 2 * D;              // 2D
  float* cbuf = vv + 2 * D;              // 16

  u16t* xhi  = (u16t*)(cbuf + 16);
  u16t* xlo  = xhi + SD;
  u16t* xT   = xlo + SD;
  u16t* wqth = xT + SD;
  u16t* wqtl = wqth + DD;
  u16t* wkth = wqtl + DD;
  u16t* wktl = wkth + DD;
  u16t* mh   = wktl + DD;
  u16t* ml   = mh + DD;
  u16t* yh   = ml + DD;
  u16t* yl   = yh + SD;
  float* band = (float*)(yl + SD);                // S*BAND f32
  u16t*  Pb   = (u16t*)(band + (size_t)S * BAND); // S*BAND u16
  float* e0d  = (float*)(Pb + (size_t)S * BAND);  // S f32
  size_t needed = (size_t)((char*)(e0d + S) - (char*)d_ws);

  if (ws_size >= needed) {
    wuv_kernel<<<dim3(16, 16, 3), 256, 0, stream>>>(
        Wq, Wk, bq, bk, uu, vv, cbuf, wqth, wqtl, wkth, wktl, xsum);
    prep_kernel<<<dim3(S / 64, D / 64), 256, 0, stream>>>(x, uu, vv, xhi, xlo, xT, xsum, a, b);
    m_kernel<<<dim3(D / 64, D / 64), 256, 0, stream>>>(wqth, wqtl, wkth, wktl, mh, ml);
    y_kernel<<<dim3(S / 128, D / 128), 256, 0, stream>>>(xhi, xlo, mh, ml, yh, yl);
    scores_kernel<<<dim3(S / 64, 5), 256, 0, stream>>>(xhi, xlo, yh, yl, a, b, cbuf, band);
    softmax_kernel<<<S / 4, 256, 0, stream>>>(band, Pb, e0d);
    pv_kernel<<<dim3(S / 64, D / 128), 256, 0, stream>>>(Pb, xT, e0d, xsum, outp);
  } else {
    float* xs2  = (float*)d_ws;
    float* q    = xs2 + D;
    float* kbuf = q + SD;
    (void)hipMemsetAsync(xs2, 0, D * sizeof(float), stream);
    colsum_kernel<<<dim3(D / 256, S / 256), 256, 0, stream>>>(x, xs2);
    proj_kernel<<<dim3(S / 64, D / 64), 256, 0, stream>>>(x, Wq, bq, Wk, bk, q, kbuf);
    attn_kernel<<<S / TQ, 256, 0, stream>>>(x, q, kbuf, xs2, outp);
  }
}